// Round 18
// baseline (472.656 us; speedup 1.0000x reference)
//
#include <hip/hip_runtime.h>
#include <stdint.h>

#define B_SZ  32
#define T_SZ  2048
#define IN_D  128
#define HID   512
#define NCHAIN 410              // ceil(T/5)
#define INV_TAUX 0.005f         // 1/200

typedef __attribute__((ext_vector_type(8))) short bf16x8;
typedef __attribute__((ext_vector_type(4))) float f32x4;
typedef __attribute__((ext_vector_type(4))) float float4v;
typedef __attribute__((ext_vector_type(4))) unsigned short u16x4;
typedef __attribute__((ext_vector_type(8))) unsigned short u16x8;

// Operands SWAPPED: mfma(b, a) => D^T. Lane holds row = frag_m*16 + (lane&15),
// cols = frag_n*16 + (lane>>4)*4 + q (4 consecutive) -> vectorized epilogues.
#define MFMA(b, a, c) __builtin_amdgcn_mfma_f32_16x16x32_bf16((b), (a), (c), 0, 0, 0)

__device__ __forceinline__ unsigned short f2bf(float x) {
  union { float f; unsigned int u; } v; v.f = x;
  unsigned int r = v.u + 0x7FFFu + ((v.u >> 16) & 1u);  // RNE
  return (unsigned short)(r >> 16);
}
__device__ __forceinline__ float bf2f(unsigned short b) {
  union { unsigned int u; float f; } v; v.u = ((unsigned int)b) << 16;
  return v.f;
}
__device__ __forceinline__ float fast_tanh(float x) {
  float ax = fabsf(x);
  float e = __expf(-2.0f * ax);
  float r = (1.0f - e) * __builtin_amdgcn_rcpf(1.0f + e);
  return x < 0.0f ? -r : r;
}
__device__ __forceinline__ void gload_lds16(const void* g, void* l) {
  __builtin_amdgcn_global_load_lds(
      reinterpret_cast<__attribute__((address_space(1))) void*>(reinterpret_cast<uintptr_t>(g)),
      reinterpret_cast<__attribute__((address_space(3))) void*>(reinterpret_cast<uintptr_t>(l)),
      16, 0, 0);
}

// ---------------------------------------------------------------------------
// ROUND-18: single change vs round 17 -- rec_all's xsall writes were 32B
// partial-line scatters (FETCH 106MB/WRITE 127MB from write-allocate RMW).
// Now: epilogue writes xnew bf16 -> sA (linear, LDS), then coalesced
// 1KB-per-wave u16x8 dump sA -> xsall (full lines). +1 barrier/step.
// ---------------------------------------------------------------------------

// ---------------------------------------------------------------------------
// enc5: 3 encoder layers + xseq dump + 2 recon-decoder layers, one kernel.
// 512 thr = 8 waves (1m x 8n), 128 rows/block, MF=8, LDS 128 KB.
// ---------------------------------------------------------------------------
__global__ __launch_bounds__(512) void enc5_k(
    const float* __restrict__ in_seq,
    const unsigned short* __restrict__ wt,
    const float* __restrict__ be1, const float* __restrict__ be2,
    const float* __restrict__ be3,
    const unsigned short* __restrict__ Wd1t,
    const unsigned short* __restrict__ Wd2t,
    const float* __restrict__ bd1, const float* __restrict__ bd2,
    unsigned short* __restrict__ xseq,
    float* __restrict__ outr)
{
  __shared__ __attribute__((aligned(16))) unsigned short sH[128 * 512];  // 128 KB
  unsigned short* sA = sH;   // alias: input tile (128x128) in sH's head

  const int tid = threadIdx.x;
  const int m0 = blockIdx.x * 128;
  const int wave = tid >> 6, lane = tid & 63;
  const int wn = wave;
  const int lrow = lane & 15, lhi = lane >> 4, sw = lrow & 7;

  // stage input tile f32 -> bf16, chunk-swizzled (128 rows x 16 chunks)
#pragma unroll
  for (int p = 0; p < 4; ++p) {
    int id = (p << 9) + tid;
    int row = id >> 4, cc = id & 15;
    const float* src = in_seq + (size_t)(m0 + row) * IN_D + (cc << 3);
    float4v u0 = *(const float4v*)src;
    float4v u1 = *(const float4v*)(src + 4);
    u16x8 h;
    h[0] = f2bf(u0[0]); h[1] = f2bf(u0[1]); h[2] = f2bf(u0[2]); h[3] = f2bf(u0[3]);
    h[4] = f2bf(u1[0]); h[5] = f2bf(u1[1]); h[6] = f2bf(u1[2]); h[7] = f2bf(u1[3]);
    int slot = (cc & 8) | ((cc & 7) ^ (row & 7));
    *(u16x8*)(sA + (row << 7) + (slot << 3)) = h;
  }
  __syncthreads();

  f32x4 acc[8][4];
  const unsigned short* Bts[3] = {wt, wt + 65536, wt + 327680};
  const float* bss[3] = {be1, be2, be3};

  // ---- 3 encoder layers (in-place in sH) ----
  for (int l = 0; l < 3; ++l) {
    const int lstr = (l == 0) ? 128 : 512;
    const int nk = (l == 0) ? 4 : 16;
    const unsigned short* bl = Bts[l] + (lane << 3);
    const int nfb = (wn << 2) * nk;
    const float* bias = bss[l];

#pragma unroll
    for (int m = 0; m < 8; ++m)
#pragma unroll
      for (int n = 0; n < 4; ++n) acc[m][n] = (f32x4){0.f, 0.f, 0.f, 0.f};

    bf16x8 b0[4], b1[4];
#pragma unroll
    for (int n = 0; n < 4; ++n)
      b0[n] = *(const bf16x8*)(bl + ((nfb + n * nk) << 9));

    for (int kk = 0; kk < nk; kk += 2) {
#pragma unroll
      for (int n = 0; n < 4; ++n)
        b1[n] = *(const bf16x8*)(bl + ((nfb + n * nk + kk + 1) << 9));
      {
        const int c = (kk << 2) + lhi;
        const int slot = (c & ~7) | ((c & 7) ^ sw);
        bf16x8 af[8];
#pragma unroll
        for (int m = 0; m < 8; ++m)
          af[m] = *(const bf16x8*)(sH + (m * 16 + lrow) * lstr + (slot << 3));
#pragma unroll
        for (int n = 0; n < 4; ++n)
#pragma unroll
          for (int m = 0; m < 8; ++m)
            acc[m][n] = MFMA(b0[n], af[m], acc[m][n]);
      }
      if (kk + 2 < nk) {
#pragma unroll
        for (int n = 0; n < 4; ++n)
          b0[n] = *(const bf16x8*)(bl + ((nfb + n * nk + kk + 2) << 9));
      }
      {
        const int c = ((kk + 1) << 2) + lhi;
        const int slot = (c & ~7) | ((c & 7) ^ sw);
        bf16x8 af[8];
#pragma unroll
        for (int m = 0; m < 8; ++m)
          af[m] = *(const bf16x8*)(sH + (m * 16 + lrow) * lstr + (slot << 3));
#pragma unroll
        for (int n = 0; n < 4; ++n)
#pragma unroll
          for (int m = 0; m < 8; ++m)
            acc[m][n] = MFMA(b1[n], af[m], acc[m][n]);
      }
    }
    __syncthreads();
    // epilogue: acc[m][n][q] = D[row=m*16+lrow][col=wn*64+n*16+lhi*4+q]
#pragma unroll
    for (int n = 0; n < 4; ++n) {
      const int col0 = (wn << 6) + n * 16 + (lhi << 2);
      const float4v bv = *(const float4v*)(bias + col0);
      const int c2 = col0 >> 3;
#pragma unroll
      for (int m = 0; m < 8; ++m) {
        const int row = m * 16 + lrow;
        const int slot2 = (c2 & ~7) | ((c2 & 7) ^ (row & 7));
        u16x4 h;
#pragma unroll
        for (int q = 0; q < 4; ++q) h[q] = f2bf(fast_tanh(acc[m][n][q] + bv[q]));
        *(u16x4*)(sH + (row << 9) + (slot2 << 3) + (col0 & 7)) = h;
      }
    }
    __syncthreads();
  }

  // ---- dump xseq (coalesced un-swizzle; read-only on sH) ----
#pragma unroll
  for (int p = 0; p < 16; ++p) {
    int id = (p << 9) + tid;
    int row = id >> 6, cc = id & 63;
    int slot = (cc & ~7) | ((cc & 7) ^ (row & 7));
    u16x8 v = *(const u16x8*)(sH + (row << 9) + (slot << 3));
    *(u16x8*)(xseq + ((size_t)(m0 + row) << 9) + (cc << 3)) = v;
  }

  // ---- recon decoder layer 1 (reads sH-as-X, writes sH-as-d1 in place) ----
#pragma unroll
  for (int m = 0; m < 8; ++m)
#pragma unroll
    for (int n = 0; n < 4; ++n) acc[m][n] = (f32x4){0.f, 0.f, 0.f, 0.f};

  {
    const unsigned short* bl = Wd1t + (lane << 3);
    const int nfb = (wn << 2) << 4;
    bf16x8 b0[4], b1[4];
#pragma unroll
    for (int n = 0; n < 4; ++n)
      b0[n] = *(const bf16x8*)(bl + ((nfb + (n << 4)) << 9));
    for (int kk = 0; kk < 16; kk += 2) {
#pragma unroll
      for (int n = 0; n < 4; ++n)
        b1[n] = *(const bf16x8*)(bl + ((nfb + (n << 4) + kk + 1) << 9));
      {
        const int c = (kk << 2) + lhi;
        const int slot = (c & ~7) | ((c & 7) ^ sw);
        bf16x8 af[8];
#pragma unroll
        for (int m = 0; m < 8; ++m)
          af[m] = *(const bf16x8*)(sH + ((m * 16 + lrow) << 9) + (slot << 3));
#pragma unroll
        for (int n = 0; n < 4; ++n)
#pragma unroll
          for (int m = 0; m < 8; ++m)
            acc[m][n] = MFMA(b0[n], af[m], acc[m][n]);
      }
      if (kk + 2 < 16) {
#pragma unroll
        for (int n = 0; n < 4; ++n)
          b0[n] = *(const bf16x8*)(bl + ((nfb + (n << 4) + kk + 2) << 9));
      }
      {
        const int c = ((kk + 1) << 2) + lhi;
        const int slot = (c & ~7) | ((c & 7) ^ sw);
        bf16x8 af[8];
#pragma unroll
        for (int m = 0; m < 8; ++m)
          af[m] = *(const bf16x8*)(sH + ((m * 16 + lrow) << 9) + (slot << 3));
#pragma unroll
        for (int n = 0; n < 4; ++n)
#pragma unroll
          for (int m = 0; m < 8; ++m)
            acc[m][n] = MFMA(b1[n], af[m], acc[m][n]);
      }
    }
  }
  __syncthreads();   // all sH(X) reads + dump reads done -> overwrite as d1
#pragma unroll
  for (int n = 0; n < 4; ++n) {
    const int col0 = (wn << 6) + n * 16 + (lhi << 2);
    const float4v bv = *(const float4v*)(bd1 + col0);
    const int c2 = col0 >> 3;
#pragma unroll
    for (int m = 0; m < 8; ++m) {
      const int row = m * 16 + lrow;
      const int slot2 = (c2 & ~7) | ((c2 & 7) ^ (row & 7));
      u16x4 h;
#pragma unroll
      for (int q = 0; q < 4; ++q) h[q] = f2bf(fast_tanh(acc[m][n][q] + bv[q]));
      *(u16x4*)(sH + (row << 9) + (slot2 << 3) + (col0 & 7)) = h;
    }
  }
  __syncthreads();

  // ---- recon decoder layer 2: N=128, wave owns one 16-col frag ----
  f32x4 acc2[8];
#pragma unroll
  for (int m = 0; m < 8; ++m) acc2[m] = (f32x4){0.f, 0.f, 0.f, 0.f};

  {
    const unsigned short* bl = Wd2t + (lane << 3);
    const int nfb = wn << 4;
    bf16x8 c0, c1;
    c0 = *(const bf16x8*)(bl + ((nfb + 0) << 9));
    for (int kk = 0; kk < 16; kk += 2) {
      c1 = *(const bf16x8*)(bl + ((nfb + kk + 1) << 9));
      {
        const int c = (kk << 2) + lhi;
        const int slot = (c & ~7) | ((c & 7) ^ sw);
#pragma unroll
        for (int m = 0; m < 8; ++m) {
          bf16x8 af = *(const bf16x8*)(sH + ((m * 16 + lrow) << 9) + (slot << 3));
          acc2[m] = MFMA(c0, af, acc2[m]);
        }
      }
      if (kk + 2 < 16)
        c0 = *(const bf16x8*)(bl + ((nfb + kk + 2) << 9));
      {
        const int c = ((kk + 1) << 2) + lhi;
        const int slot = (c & ~7) | ((c & 7) ^ sw);
#pragma unroll
        for (int m = 0; m < 8; ++m) {
          bf16x8 af = *(const bf16x8*)(sH + ((m * 16 + lrow) << 9) + (slot << 3));
          acc2[m] = MFMA(c1, af, acc2[m]);
        }
      }
    }
  }
  {
    const int col0 = (wn << 4) + (lhi << 2);
    const float4v bv = *(const float4v*)(bd2 + col0);
#pragma unroll
    for (int m = 0; m < 8; ++m) {
      const int row = m * 16 + lrow;
      float4v o;
#pragma unroll
      for (int q = 0; q < 4; ++q) o[q] = fast_tanh(acc2[m][q] + bv[q]);
      *(float4v*)(outr + (size_t)(m0 + row) * IN_D + col0) = o;
    }
  }
}

// ---------------------------------------------------------------------------
// Fused 2-layer decoder (pred pass). 1024 thr = 16 waves (2wm x 8wn),
// 128 rows/block, MF=4.
// ---------------------------------------------------------------------------
__global__ __launch_bounds__(1024) void dec_fused_k(
    const unsigned short* __restrict__ X,
    const unsigned short* __restrict__ Wd1t,
    const unsigned short* __restrict__ Wd2t,
    const float* __restrict__ bd1, const float* __restrict__ bd2,
    float* __restrict__ out)
{
  __shared__ __attribute__((aligned(16))) unsigned short sH[128 * 512];  // 128 KB
  unsigned short* sX = sH;

  const int tid = threadIdx.x;
  const int m0 = blockIdx.x * 128;
  const int wave = tid >> 6, lane = tid & 63;
  const int wm = wave >> 3, wn = wave & 7;
  const int rb = wm << 6;
  const int lrow = lane & 15, lhi = lane >> 4, sw = lrow & 7;

  char* lX = (char*)sX + tid * 16;
#pragma unroll
  for (int p = 0; p < 8; ++p) {
    int id = (p << 10) + tid;
    int row = id >> 6, cc = id & 63;
    int gcc = (cc & ~7) | ((cc & 7) ^ (row & 7));
    gload_lds16(X + ((size_t)(m0 + row) << 9) + (gcc << 3), lX + (p << 14));
  }
  __syncthreads();

  f32x4 acc[4][4];
#pragma unroll
  for (int m = 0; m < 4; ++m)
#pragma unroll
    for (int n = 0; n < 4; ++n) acc[m][n] = (f32x4){0.f, 0.f, 0.f, 0.f};

  {
    const unsigned short* bl = Wd1t + (lane << 3);
    const int nfb = (wn << 2) << 4;
    bf16x8 b0[4], b1[4];
#pragma unroll
    for (int n = 0; n < 4; ++n)
      b0[n] = *(const bf16x8*)(bl + ((nfb + (n << 4)) << 9));
    for (int kk = 0; kk < 16; kk += 2) {
#pragma unroll
      for (int n = 0; n < 4; ++n)
        b1[n] = *(const bf16x8*)(bl + ((nfb + (n << 4) + kk + 1) << 9));
      {
        const int c = (kk << 2) + lhi;
        const int slot = (c & ~7) | ((c & 7) ^ sw);
        bf16x8 af[4];
#pragma unroll
        for (int m = 0; m < 4; ++m)
          af[m] = *(const bf16x8*)(sX + ((rb + m * 16 + lrow) << 9) + (slot << 3));
#pragma unroll
        for (int n = 0; n < 4; ++n)
#pragma unroll
          for (int m = 0; m < 4; ++m)
            acc[m][n] = MFMA(b0[n], af[m], acc[m][n]);
      }
      if (kk + 2 < 16) {
#pragma unroll
        for (int n = 0; n < 4; ++n)
          b0[n] = *(const bf16x8*)(bl + ((nfb + (n << 4) + kk + 2) << 9));
      }
      {
        const int c = ((kk + 1) << 2) + lhi;
        const int slot = (c & ~7) | ((c & 7) ^ sw);
        bf16x8 af[4];
#pragma unroll
        for (int m = 0; m < 4; ++m)
          af[m] = *(const bf16x8*)(sX + ((rb + m * 16 + lrow) << 9) + (slot << 3));
#pragma unroll
        for (int n = 0; n < 4; ++n)
#pragma unroll
          for (int m = 0; m < 4; ++m)
            acc[m][n] = MFMA(b1[n], af[m], acc[m][n]);
      }
    }
  }
  __syncthreads();
#pragma unroll
  for (int n = 0; n < 4; ++n) {
    const int col0 = (wn << 6) + n * 16 + (lhi << 2);
    const float4v bv = *(const float4v*)(bd1 + col0);
    const int c2 = col0 >> 3;
#pragma unroll
    for (int m = 0; m < 4; ++m) {
      const int row = rb + m * 16 + lrow;
      const int slot2 = (c2 & ~7) | ((c2 & 7) ^ (row & 7));
      u16x4 h;
#pragma unroll
      for (int q = 0; q < 4; ++q) h[q] = f2bf(fast_tanh(acc[m][n][q] + bv[q]));
      *(u16x4*)(sH + (row << 9) + (slot2 << 3) + (col0 & 7)) = h;
    }
  }
  __syncthreads();

  f32x4 acc2[4];
#pragma unroll
  for (int m = 0; m < 4; ++m) acc2[m] = (f32x4){0.f, 0.f, 0.f, 0.f};

  {
    const unsigned short* bl = Wd2t + (lane << 3);
    const int nfb = wn << 4;
    bf16x8 c0, c1;
    c0 = *(const bf16x8*)(bl + ((nfb + 0) << 9));
    for (int kk = 0; kk < 16; kk += 2) {
      c1 = *(const bf16x8*)(bl + ((nfb + kk + 1) << 9));
      {
        const int c = (kk << 2) + lhi;
        const int slot = (c & ~7) | ((c & 7) ^ sw);
#pragma unroll
        for (int m = 0; m < 4; ++m) {
          bf16x8 af = *(const bf16x8*)(sH + ((rb + m * 16 + lrow) << 9) + (slot << 3));
          acc2[m] = MFMA(c0, af, acc2[m]);
        }
      }
      if (kk + 2 < 16)
        c0 = *(const bf16x8*)(bl + ((nfb + kk + 2) << 9));
      {
        const int c = ((kk + 1) << 2) + lhi;
        const int slot = (c & ~7) | ((c & 7) ^ sw);
#pragma unroll
        for (int m = 0; m < 4; ++m) {
          bf16x8 af = *(const bf16x8*)(sH + ((rb + m * 16 + lrow) << 9) + (slot << 3));
          acc2[m] = MFMA(c1, af, acc2[m]);
        }
      }
    }
  }
  {
    const int col0 = (wn << 4) + (lhi << 2);
    const float4v bv = *(const float4v*)(bd2 + col0);
#pragma unroll
    for (int m = 0; m < 4; ++m) {
      const int row = rb + m * 16 + lrow;
      float4v o;
#pragma unroll
      for (int q = 0; q < 4; ++q) o[q] = fast_tanh(acc2[m][q] + bv[q]);
      *(float4v*)(out + (size_t)(m0 + row) * IN_D + col0) = o;
    }
  }
}

// ---------------------------------------------------------------------------
// rec_all: ALL 5 recurrence steps in one kernel. Block = one chain (32 rows).
// xsall writes now staged through sA (linear) + coalesced 1KB dump.
// ---------------------------------------------------------------------------
__global__ __launch_bounds__(512) void rec_all_k(
    const unsigned short* __restrict__ Wrec,
    unsigned short* __restrict__ xsall)   // in: xseq rows at t0; out: pred states
{
  __shared__ float xst[32][516];                                        // 64.5 KB
  __shared__ __attribute__((aligned(16))) unsigned short sA[32 * 512];  // 32 KB

  const int tid = threadIdx.x;
  const int chain = blockIdx.x;
  const int t0 = chain * 5;
  const int wave = tid >> 6, lane = tid & 63;
  const int wn = wave;
  const int lrow = lane & 15, lhi = lane >> 4, sw = lrow & 7;

  // coalesced init: xsall[row, t0, :] bf16 -> xst f32
#pragma unroll
  for (int p = 0; p < 4; ++p) {
    int id = (p << 9) + tid;
    int row = id >> 6, c8 = (id & 63) << 3;
    u16x8 v = *(const u16x8*)(xsall + (((size_t)row * T_SZ + t0) << 9) + c8);
#pragma unroll
    for (int e = 0; e < 8; ++e) xst[row][c8 + e] = bf2f(v[e]);
  }
  __syncthreads();

  const unsigned short* bl = Wrec + (lane << 3);
  const int nfb = (wn << 2) << 4;

  for (int s = 0; s < 5; ++s) {
    // stage tanh(xst) -> sA (swizzled)
#pragma unroll
    for (int p = 0; p < 4; ++p) {
      int id = (p << 9) + tid;
      int row = id >> 6, cc = id & 63;
      int gc = (cc & ~7) | ((cc & 7) ^ (row & 7));
      const float* src = &xst[row][gc << 3];
      float4v u0 = *(const float4v*)src;
      float4v u1 = *(const float4v*)(src + 4);
      u16x8 h;
      h[0] = f2bf(fast_tanh(u0[0])); h[1] = f2bf(fast_tanh(u0[1]));
      h[2] = f2bf(fast_tanh(u0[2])); h[3] = f2bf(fast_tanh(u0[3]));
      h[4] = f2bf(fast_tanh(u1[0])); h[5] = f2bf(fast_tanh(u1[1]));
      h[6] = f2bf(fast_tanh(u1[2])); h[7] = f2bf(fast_tanh(u1[3]));
      *(u16x8*)(sA + (row << 9) + (cc << 3)) = h;
    }
    __syncthreads();

    f32x4 acc[2][4];
#pragma unroll
    for (int m = 0; m < 2; ++m)
#pragma unroll
      for (int n = 0; n < 4; ++n) acc[m][n] = (f32x4){0.f, 0.f, 0.f, 0.f};

    bf16x8 b0[4], b1[4];
#pragma unroll
    for (int n = 0; n < 4; ++n)
      b0[n] = *(const bf16x8*)(bl + ((nfb + (n << 4)) << 9));
    for (int kk = 0; kk < 16; kk += 2) {
#pragma unroll
      for (int n = 0; n < 4; ++n)
        b1[n] = *(const bf16x8*)(bl + ((nfb + (n << 4) + kk + 1) << 9));
      {
        const int c = (kk << 2) + lhi;
        const int slot = (c & ~7) | ((c & 7) ^ sw);
        bf16x8 af0 = *(const bf16x8*)(sA + (lrow << 9) + (slot << 3));
        bf16x8 af1 = *(const bf16x8*)(sA + ((16 + lrow) << 9) + (slot << 3));
#pragma unroll
        for (int n = 0; n < 4; ++n) {
          acc[0][n] = MFMA(b0[n], af0, acc[0][n]);
          acc[1][n] = MFMA(b0[n], af1, acc[1][n]);
        }
      }
      if (kk + 2 < 16) {
#pragma unroll
        for (int n = 0; n < 4; ++n)
          b0[n] = *(const bf16x8*)(bl + ((nfb + (n << 4) + kk + 2) << 9));
      }
      {
        const int c = ((kk + 1) << 2) + lhi;
        const int slot = (c & ~7) | ((c & 7) ^ sw);
        bf16x8 af0 = *(const bf16x8*)(sA + (lrow << 9) + (slot << 3));
        bf16x8 af1 = *(const bf16x8*)(sA + ((16 + lrow) << 9) + (slot << 3));
#pragma unroll
        for (int n = 0; n < 4; ++n) {
          acc[0][n] = MFMA(b1[n], af0, acc[0][n]);
          acc[1][n] = MFMA(b1[n], af1, acc[1][n]);
        }
      }
    }
    __syncthreads();   // all k-loop reads of sA complete -> safe to overwrite

    // epilogue: update xst in place + write xnew bf16 into sA (LINEAR)
#pragma unroll
    for (int n = 0; n < 4; ++n) {
      const int col0 = (wn << 6) + n * 16 + (lhi << 2);
#pragma unroll
      for (int m = 0; m < 2; ++m) {
        const int row = m * 16 + lrow;
        float4v x = *(const float4v*)(&xst[row][col0]);
        float4v xn;
        u16x4 h;
#pragma unroll
        for (int q = 0; q < 4; ++q) {
          xn[q] = x[q] + (acc[m][n][q] - x[q]) * INV_TAUX;
          h[q] = f2bf(xn[q]);
        }
        *(float4v*)(&xst[row][col0]) = xn;
        *(u16x4*)(sA + (row << 9) + col0) = h;
      }
    }
    __syncthreads();   // sA fully written by all waves

    // coalesced dump: sA -> xsall[:, t, :] (1KB full lines per wave)
    const int t = t0 + s;
    if (t < T_SZ) {
#pragma unroll
      for (int p = 0; p < 4; ++p) {
        int id = (p << 9) + tid;
        int row = id >> 6, c8 = (id & 63) << 3;
        u16x8 v = *(const u16x8*)(sA + (row << 9) + c8);
        *(u16x8*)(xsall + (((size_t)row * T_SZ + t) << 9) + c8) = v;
      }
    }
    __syncthreads();   // dump reads done before next step's staging overwrites
  }
}

// weight prep into fragment-linear layout:
// flat[((nf*nk+kk)*64+lane)*8+e] = B[nf*16+(lane&15)][kk*32+(lane>>4)*8+e]
__global__ void prep_k(const float* __restrict__ We1, const float* __restrict__ We2,
                       const float* __restrict__ We3, const float* __restrict__ Wd1,
                       const float* __restrict__ Wd2, const float* __restrict__ W,
                       unsigned short* __restrict__ wt) {
  int idx = blockIdx.x * blockDim.x + threadIdx.x;
  if (idx >= 1179648) return;
  unsigned short v;
  if (idx < 65536) {
    int i = idx, lane = (i >> 3) & 63, t2 = i >> 9;
    int kk = t2 & 3, nf = t2 >> 2;
    int n = (nf << 4) + (lane & 15), k = (kk << 5) + ((lane >> 4) << 3) + (i & 7);
    v = f2bf(We1[k * 512 + n]);
  } else if (idx < 327680) {
    int i = idx - 65536, lane = (i >> 3) & 63, t2 = i >> 9;
    int kk = t2 & 15, nf = t2 >> 4;
    int n = (nf << 4) + (lane & 15), k = (kk << 5) + ((lane >> 4) << 3) + (i & 7);
    v = f2bf(We2[k * 512 + n]);
  } else if (idx < 589824) {
    int i = idx - 327680, lane = (i >> 3) & 63, t2 = i >> 9;
    int kk = t2 & 15, nf = t2 >> 4;
    int n = (nf << 4) + (lane & 15), k = (kk << 5) + ((lane >> 4) << 3) + (i & 7);
    v = f2bf(We3[k * 512 + n]);
  } else if (idx < 851968) {
    int i = idx - 589824, lane = (i >> 3) & 63, t2 = i >> 9;
    int kk = t2 & 15, nf = t2 >> 4;
    int n = (nf << 4) + (lane & 15), k = (kk << 5) + ((lane >> 4) << 3) + (i & 7);
    v = f2bf(Wd1[k * 512 + n]);
  } else if (idx < 917504) {
    int i = idx - 851968, lane = (i >> 3) & 63, t2 = i >> 9;
    int kk = t2 & 15, nf = t2 >> 4;
    int n = (nf << 4) + (lane & 15), k = (kk << 5) + ((lane >> 4) << 3) + (i & 7);
    v = f2bf(Wd2[k * 128 + n]);
  } else {
    int i = idx - 917504, lane = (i >> 3) & 63, t2 = i >> 9;
    int kk = t2 & 15, nf = t2 >> 4;
    int n = (nf << 4) + (lane & 15), k = (kk << 5) + ((lane >> 4) << 3) + (i & 7);
    v = f2bf(W[(n << 9) + k]);
  }
  wt[idx] = v;
}

__global__ void sentinel_k(float* out, float v) { out[0] = v; }

extern "C" void kernel_launch(void* const* d_in, const int* in_sizes, int n_in,
                              void* d_out, int out_size, void* d_ws, size_t ws_size,
                              hipStream_t stream) {
  const float* in_seq = (const float*)d_in[0];
  const float* We1 = (const float*)d_in[1];
  const float* be1 = (const float*)d_in[2];
  const float* We2 = (const float*)d_in[3];
  const float* be2 = (const float*)d_in[4];
  const float* We3 = (const float*)d_in[5];
  const float* be3 = (const float*)d_in[6];
  const float* Wd1 = (const float*)d_in[7];
  const float* bd1 = (const float*)d_in[8];
  const float* Wd2 = (const float*)d_in[9];
  const float* bd2 = (const float*)d_in[10];
  const float* W   = (const float*)d_in[11];

  const int NROW = B_SZ * T_SZ;                       // 65536
  const size_t OFF_XSEQ = 0;                          // 67,108,864 B
  const size_t OFF_WT   = (size_t)NROW * HID * 2;     // 67,108,864
  const size_t REQUIRED = OFF_WT + 2359296;           // 69,468,160

  float* outp = (float*)d_out;
  float* outr = outp + (size_t)NROW * IN_D;

  if (ws_size < REQUIRED) {
    sentinel_k<<<1, 1, 0, stream>>>(outp, (float)(ws_size >> 20));
    return;
  }

  char* ws = (char*)d_ws;
  unsigned short* xseq = (unsigned short*)(ws + OFF_XSEQ);  // reused as xsall
  unsigned short* wt   = (unsigned short*)(ws + OFF_WT);
  unsigned short* Wd1t = wt + 589824;
  unsigned short* Wd2t = wt + 851968;
  unsigned short* Wrec = wt + 917504;

  prep_k<<<4608, 256, 0, stream>>>(We1, We2, We3, Wd1, Wd2, W, wt);
  enc5_k<<<512, 512, 0, stream>>>(in_seq, wt, be1, be2, be3,
                                  Wd1t, Wd2t, bd1, bd2, xseq, outr);
  rec_all_k<<<NCHAIN, 512, 0, stream>>>(Wrec, xseq);
  dec_fused_k<<<512, 1024, 0, stream>>>(xseq, Wd1t, Wd2t, bd1, bd2, outp);
}

// Round 19
// 461.626 us; speedup vs baseline: 1.0239x; 1.0239x over previous
//
#include <hip/hip_runtime.h>
#include <stdint.h>

#define B_SZ  32
#define T_SZ  2048
#define IN_D  128
#define HID   512
#define NCHAIN 410              // ceil(T/5)
#define INV_TAUX 0.005f         // 1/200

typedef __attribute__((ext_vector_type(8))) short bf16x8;
typedef __attribute__((ext_vector_type(4))) float f32x4;
typedef __attribute__((ext_vector_type(4))) float float4v;
typedef __attribute__((ext_vector_type(4))) unsigned short u16x4;
typedef __attribute__((ext_vector_type(8))) unsigned short u16x8;

// Operands SWAPPED: mfma(b, a) => D^T. Lane holds row = frag_m*16 + (lane&15),
// cols = frag_n*16 + (lane>>4)*4 + q (4 consecutive) -> vectorized epilogues.
#define MFMA(b, a, c) __builtin_amdgcn_mfma_f32_16x16x32_bf16((b), (a), (c), 0, 0, 0)

__device__ __forceinline__ unsigned short f2bf(float x) {
  union { float f; unsigned int u; } v; v.f = x;
  unsigned int r = v.u + 0x7FFFu + ((v.u >> 16) & 1u);  // RNE
  return (unsigned short)(r >> 16);
}
__device__ __forceinline__ float bf2f(unsigned short b) {
  union { unsigned int u; float f; } v; v.u = ((unsigned int)b) << 16;
  return v.f;
}
__device__ __forceinline__ float fast_tanh(float x) {
  float ax = fabsf(x);
  float e = __expf(-2.0f * ax);
  float r = (1.0f - e) * __builtin_amdgcn_rcpf(1.0f + e);
  return x < 0.0f ? -r : r;
}
__device__ __forceinline__ void gload_lds16(const void* g, void* l) {
  __builtin_amdgcn_global_load_lds(
      reinterpret_cast<__attribute__((address_space(1))) void*>(reinterpret_cast<uintptr_t>(g)),
      reinterpret_cast<__attribute__((address_space(3))) void*>(reinterpret_cast<uintptr_t>(l)),
      16, 0, 0);
}

// ---------------------------------------------------------------------------
// ROUND-19: per-kernel measured winners. enc5 = R13 config (64 rows, 512 thr,
// MF=4, 64KB LDS: 214us vs 228/242 for MF=8/1024thr). dec = R16/18 config
// (128 rows, 1024 thr: ~15us faster than 512-thr). rec_all = R18 (coalesced
// sA-staged xsall dump, kills write-allocate RMW).
// ---------------------------------------------------------------------------

// ---------------------------------------------------------------------------
// enc5: 3 encoder layers + xseq dump + 2 recon-decoder layers, one kernel.
// 512 thr = 8 waves (1m x 8n), 64 rows/block, LDS 64 KB.
// ---------------------------------------------------------------------------
__global__ __launch_bounds__(512) void enc5_k(
    const float* __restrict__ in_seq,
    const unsigned short* __restrict__ wt,
    const float* __restrict__ be1, const float* __restrict__ be2,
    const float* __restrict__ be3,
    const unsigned short* __restrict__ Wd1t,
    const unsigned short* __restrict__ Wd2t,
    const float* __restrict__ bd1, const float* __restrict__ bd2,
    unsigned short* __restrict__ xseq,
    float* __restrict__ outr)
{
  __shared__ __attribute__((aligned(16))) unsigned short sH[64 * 512];  // 64 KB
  unsigned short* sA = sH;   // alias: input tile (64x128) in sH's head

  const int tid = threadIdx.x;
  const int m0 = blockIdx.x * 64;
  const int wave = tid >> 6, lane = tid & 63;
  const int wn = wave;
  const int lrow = lane & 15, lhi = lane >> 4, sw = lrow & 7;

  // stage input tile f32 -> bf16, chunk-swizzled
#pragma unroll
  for (int p = 0; p < 2; ++p) {
    int id = (p << 9) + tid;
    int row = id >> 4, cc = id & 15;
    const float* src = in_seq + (size_t)(m0 + row) * IN_D + (cc << 3);
    float4v u0 = *(const float4v*)src;
    float4v u1 = *(const float4v*)(src + 4);
    u16x8 h;
    h[0] = f2bf(u0[0]); h[1] = f2bf(u0[1]); h[2] = f2bf(u0[2]); h[3] = f2bf(u0[3]);
    h[4] = f2bf(u1[0]); h[5] = f2bf(u1[1]); h[6] = f2bf(u1[2]); h[7] = f2bf(u1[3]);
    int slot = (cc & 8) | ((cc & 7) ^ (row & 7));
    *(u16x8*)(sA + (row << 7) + (slot << 3)) = h;
  }
  __syncthreads();

  f32x4 acc[4][4];
  const unsigned short* Bts[3] = {wt, wt + 65536, wt + 327680};
  const float* bss[3] = {be1, be2, be3};

  // ---- 3 encoder layers (in-place in sH) ----
  for (int l = 0; l < 3; ++l) {
    const int lstr = (l == 0) ? 128 : 512;
    const int nk = (l == 0) ? 4 : 16;
    const unsigned short* bl = Bts[l] + (lane << 3);
    const int nfb = (wn << 2) * nk;
    const float* bias = bss[l];

#pragma unroll
    for (int m = 0; m < 4; ++m)
#pragma unroll
      for (int n = 0; n < 4; ++n) acc[m][n] = (f32x4){0.f, 0.f, 0.f, 0.f};

    bf16x8 b0[4], b1[4];
#pragma unroll
    for (int n = 0; n < 4; ++n)
      b0[n] = *(const bf16x8*)(bl + ((nfb + n * nk) << 9));

    for (int kk = 0; kk < nk; kk += 2) {
#pragma unroll
      for (int n = 0; n < 4; ++n)
        b1[n] = *(const bf16x8*)(bl + ((nfb + n * nk + kk + 1) << 9));
      {
        const int c = (kk << 2) + lhi;
        const int slot = (c & ~7) | ((c & 7) ^ sw);
        bf16x8 af[4];
#pragma unroll
        for (int m = 0; m < 4; ++m)
          af[m] = *(const bf16x8*)(sH + (m * 16 + lrow) * lstr + (slot << 3));
#pragma unroll
        for (int n = 0; n < 4; ++n)
#pragma unroll
          for (int m = 0; m < 4; ++m)
            acc[m][n] = MFMA(b0[n], af[m], acc[m][n]);
      }
      if (kk + 2 < nk) {
#pragma unroll
        for (int n = 0; n < 4; ++n)
          b0[n] = *(const bf16x8*)(bl + ((nfb + n * nk + kk + 2) << 9));
      }
      {
        const int c = ((kk + 1) << 2) + lhi;
        const int slot = (c & ~7) | ((c & 7) ^ sw);
        bf16x8 af[4];
#pragma unroll
        for (int m = 0; m < 4; ++m)
          af[m] = *(const bf16x8*)(sH + (m * 16 + lrow) * lstr + (slot << 3));
#pragma unroll
        for (int n = 0; n < 4; ++n)
#pragma unroll
          for (int m = 0; m < 4; ++m)
            acc[m][n] = MFMA(b1[n], af[m], acc[m][n]);
      }
    }
    __syncthreads();
    // epilogue: acc[m][n][q] = D[row=m*16+lrow][col=wn*64+n*16+lhi*4+q]
#pragma unroll
    for (int n = 0; n < 4; ++n) {
      const int col0 = (wn << 6) + n * 16 + (lhi << 2);
      const float4v bv = *(const float4v*)(bias + col0);
      const int c2 = col0 >> 3;
#pragma unroll
      for (int m = 0; m < 4; ++m) {
        const int row = m * 16 + lrow;
        const int slot2 = (c2 & ~7) | ((c2 & 7) ^ (row & 7));
        u16x4 h;
#pragma unroll
        for (int q = 0; q < 4; ++q) h[q] = f2bf(fast_tanh(acc[m][n][q] + bv[q]));
        *(u16x4*)(sH + (row << 9) + (slot2 << 3) + (col0 & 7)) = h;
      }
    }
    __syncthreads();
  }

  // ---- dump xseq (coalesced un-swizzle; read-only on sH) ----
#pragma unroll
  for (int p = 0; p < 8; ++p) {
    int id = (p << 9) + tid;
    int row = id >> 6, cc = id & 63;
    int slot = (cc & ~7) | ((cc & 7) ^ (row & 7));
    u16x8 v = *(const u16x8*)(sH + (row << 9) + (slot << 3));
    *(u16x8*)(xseq + ((size_t)(m0 + row) << 9) + (cc << 3)) = v;
  }

  // ---- recon decoder layer 1 (reads sH-as-X, writes sH-as-d1 in place) ----
#pragma unroll
  for (int m = 0; m < 4; ++m)
#pragma unroll
    for (int n = 0; n < 4; ++n) acc[m][n] = (f32x4){0.f, 0.f, 0.f, 0.f};

  {
    const unsigned short* bl = Wd1t + (lane << 3);
    const int nfb = (wn << 2) << 4;
    bf16x8 b0[4], b1[4];
#pragma unroll
    for (int n = 0; n < 4; ++n)
      b0[n] = *(const bf16x8*)(bl + ((nfb + (n << 4)) << 9));
    for (int kk = 0; kk < 16; kk += 2) {
#pragma unroll
      for (int n = 0; n < 4; ++n)
        b1[n] = *(const bf16x8*)(bl + ((nfb + (n << 4) + kk + 1) << 9));
      {
        const int c = (kk << 2) + lhi;
        const int slot = (c & ~7) | ((c & 7) ^ sw);
        bf16x8 af[4];
#pragma unroll
        for (int m = 0; m < 4; ++m)
          af[m] = *(const bf16x8*)(sH + ((m * 16 + lrow) << 9) + (slot << 3));
#pragma unroll
        for (int n = 0; n < 4; ++n)
#pragma unroll
          for (int m = 0; m < 4; ++m)
            acc[m][n] = MFMA(b0[n], af[m], acc[m][n]);
      }
      if (kk + 2 < 16) {
#pragma unroll
        for (int n = 0; n < 4; ++n)
          b0[n] = *(const bf16x8*)(bl + ((nfb + (n << 4) + kk + 2) << 9));
      }
      {
        const int c = ((kk + 1) << 2) + lhi;
        const int slot = (c & ~7) | ((c & 7) ^ sw);
        bf16x8 af[4];
#pragma unroll
        for (int m = 0; m < 4; ++m)
          af[m] = *(const bf16x8*)(sH + ((m * 16 + lrow) << 9) + (slot << 3));
#pragma unroll
        for (int n = 0; n < 4; ++n)
#pragma unroll
          for (int m = 0; m < 4; ++m)
            acc[m][n] = MFMA(b1[n], af[m], acc[m][n]);
      }
    }
  }
  __syncthreads();   // all sH(X) reads + dump reads done -> overwrite as d1
#pragma unroll
  for (int n = 0; n < 4; ++n) {
    const int col0 = (wn << 6) + n * 16 + (lhi << 2);
    const float4v bv = *(const float4v*)(bd1 + col0);
    const int c2 = col0 >> 3;
#pragma unroll
    for (int m = 0; m < 4; ++m) {
      const int row = m * 16 + lrow;
      const int slot2 = (c2 & ~7) | ((c2 & 7) ^ (row & 7));
      u16x4 h;
#pragma unroll
      for (int q = 0; q < 4; ++q) h[q] = f2bf(fast_tanh(acc[m][n][q] + bv[q]));
      *(u16x4*)(sH + (row << 9) + (slot2 << 3) + (col0 & 7)) = h;
    }
  }
  __syncthreads();

  // ---- recon decoder layer 2: N=128, wave owns one 16-col frag ----
  f32x4 acc2[4];
#pragma unroll
  for (int m = 0; m < 4; ++m) acc2[m] = (f32x4){0.f, 0.f, 0.f, 0.f};

  {
    const unsigned short* bl = Wd2t + (lane << 3);
    const int nfb = wn << 4;
    bf16x8 c0, c1;
    c0 = *(const bf16x8*)(bl + ((nfb + 0) << 9));
    for (int kk = 0; kk < 16; kk += 2) {
      c1 = *(const bf16x8*)(bl + ((nfb + kk + 1) << 9));
      {
        const int c = (kk << 2) + lhi;
        const int slot = (c & ~7) | ((c & 7) ^ sw);
#pragma unroll
        for (int m = 0; m < 4; ++m) {
          bf16x8 af = *(const bf16x8*)(sH + ((m * 16 + lrow) << 9) + (slot << 3));
          acc2[m] = MFMA(c0, af, acc2[m]);
        }
      }
      if (kk + 2 < 16)
        c0 = *(const bf16x8*)(bl + ((nfb + kk + 2) << 9));
      {
        const int c = ((kk + 1) << 2) + lhi;
        const int slot = (c & ~7) | ((c & 7) ^ sw);
#pragma unroll
        for (int m = 0; m < 4; ++m) {
          bf16x8 af = *(const bf16x8*)(sH + ((m * 16 + lrow) << 9) + (slot << 3));
          acc2[m] = MFMA(c1, af, acc2[m]);
        }
      }
    }
  }
  {
    const int col0 = (wn << 4) + (lhi << 2);
    const float4v bv = *(const float4v*)(bd2 + col0);
#pragma unroll
    for (int m = 0; m < 4; ++m) {
      const int row = m * 16 + lrow;
      float4v o;
#pragma unroll
      for (int q = 0; q < 4; ++q) o[q] = fast_tanh(acc2[m][q] + bv[q]);
      *(float4v*)(outr + (size_t)(m0 + row) * IN_D + col0) = o;
    }
  }
}

// ---------------------------------------------------------------------------
// Fused 2-layer decoder (pred pass). 1024 thr = 16 waves (2wm x 8wn),
// 128 rows/block, MF=4.
// ---------------------------------------------------------------------------
__global__ __launch_bounds__(1024) void dec_fused_k(
    const unsigned short* __restrict__ X,
    const unsigned short* __restrict__ Wd1t,
    const unsigned short* __restrict__ Wd2t,
    const float* __restrict__ bd1, const float* __restrict__ bd2,
    float* __restrict__ out)
{
  __shared__ __attribute__((aligned(16))) unsigned short sH[128 * 512];  // 128 KB
  unsigned short* sX = sH;

  const int tid = threadIdx.x;
  const int m0 = blockIdx.x * 128;
  const int wave = tid >> 6, lane = tid & 63;
  const int wm = wave >> 3, wn = wave & 7;
  const int rb = wm << 6;
  const int lrow = lane & 15, lhi = lane >> 4, sw = lrow & 7;

  char* lX = (char*)sX + tid * 16;
#pragma unroll
  for (int p = 0; p < 8; ++p) {
    int id = (p << 10) + tid;
    int row = id >> 6, cc = id & 63;
    int gcc = (cc & ~7) | ((cc & 7) ^ (row & 7));
    gload_lds16(X + ((size_t)(m0 + row) << 9) + (gcc << 3), lX + (p << 14));
  }
  __syncthreads();

  f32x4 acc[4][4];
#pragma unroll
  for (int m = 0; m < 4; ++m)
#pragma unroll
    for (int n = 0; n < 4; ++n) acc[m][n] = (f32x4){0.f, 0.f, 0.f, 0.f};

  {
    const unsigned short* bl = Wd1t + (lane << 3);
    const int nfb = (wn << 2) << 4;
    bf16x8 b0[4], b1[4];
#pragma unroll
    for (int n = 0; n < 4; ++n)
      b0[n] = *(const bf16x8*)(bl + ((nfb + (n << 4)) << 9));
    for (int kk = 0; kk < 16; kk += 2) {
#pragma unroll
      for (int n = 0; n < 4; ++n)
        b1[n] = *(const bf16x8*)(bl + ((nfb + (n << 4) + kk + 1) << 9));
      {
        const int c = (kk << 2) + lhi;
        const int slot = (c & ~7) | ((c & 7) ^ sw);
        bf16x8 af[4];
#pragma unroll
        for (int m = 0; m < 4; ++m)
          af[m] = *(const bf16x8*)(sX + ((rb + m * 16 + lrow) << 9) + (slot << 3));
#pragma unroll
        for (int n = 0; n < 4; ++n)
#pragma unroll
          for (int m = 0; m < 4; ++m)
            acc[m][n] = MFMA(b0[n], af[m], acc[m][n]);
      }
      if (kk + 2 < 16) {
#pragma unroll
        for (int n = 0; n < 4; ++n)
          b0[n] = *(const bf16x8*)(bl + ((nfb + (n << 4) + kk + 2) << 9));
      }
      {
        const int c = ((kk + 1) << 2) + lhi;
        const int slot = (c & ~7) | ((c & 7) ^ sw);
        bf16x8 af[4];
#pragma unroll
        for (int m = 0; m < 4; ++m)
          af[m] = *(const bf16x8*)(sX + ((rb + m * 16 + lrow) << 9) + (slot << 3));
#pragma unroll
        for (int n = 0; n < 4; ++n)
#pragma unroll
          for (int m = 0; m < 4; ++m)
            acc[m][n] = MFMA(b1[n], af[m], acc[m][n]);
      }
    }
  }
  __syncthreads();
#pragma unroll
  for (int n = 0; n < 4; ++n) {
    const int col0 = (wn << 6) + n * 16 + (lhi << 2);
    const float4v bv = *(const float4v*)(bd1 + col0);
    const int c2 = col0 >> 3;
#pragma unroll
    for (int m = 0; m < 4; ++m) {
      const int row = rb + m * 16 + lrow;
      const int slot2 = (c2 & ~7) | ((c2 & 7) ^ (row & 7));
      u16x4 h;
#pragma unroll
      for (int q = 0; q < 4; ++q) h[q] = f2bf(fast_tanh(acc[m][n][q] + bv[q]));
      *(u16x4*)(sH + (row << 9) + (slot2 << 3) + (col0 & 7)) = h;
    }
  }
  __syncthreads();

  f32x4 acc2[4];
#pragma unroll
  for (int m = 0; m < 4; ++m) acc2[m] = (f32x4){0.f, 0.f, 0.f, 0.f};

  {
    const unsigned short* bl = Wd2t + (lane << 3);
    const int nfb = wn << 4;
    bf16x8 c0, c1;
    c0 = *(const bf16x8*)(bl + ((nfb + 0) << 9));
    for (int kk = 0; kk < 16; kk += 2) {
      c1 = *(const bf16x8*)(bl + ((nfb + kk + 1) << 9));
      {
        const int c = (kk << 2) + lhi;
        const int slot = (c & ~7) | ((c & 7) ^ sw);
#pragma unroll
        for (int m = 0; m < 4; ++m) {
          bf16x8 af = *(const bf16x8*)(sH + ((rb + m * 16 + lrow) << 9) + (slot << 3));
          acc2[m] = MFMA(c0, af, acc2[m]);
        }
      }
      if (kk + 2 < 16)
        c0 = *(const bf16x8*)(bl + ((nfb + kk + 2) << 9));
      {
        const int c = ((kk + 1) << 2) + lhi;
        const int slot = (c & ~7) | ((c & 7) ^ sw);
#pragma unroll
        for (int m = 0; m < 4; ++m) {
          bf16x8 af = *(const bf16x8*)(sH + ((rb + m * 16 + lrow) << 9) + (slot << 3));
          acc2[m] = MFMA(c1, af, acc2[m]);
        }
      }
    }
  }
  {
    const int col0 = (wn << 4) + (lhi << 2);
    const float4v bv = *(const float4v*)(bd2 + col0);
#pragma unroll
    for (int m = 0; m < 4; ++m) {
      const int row = rb + m * 16 + lrow;
      float4v o;
#pragma unroll
      for (int q = 0; q < 4; ++q) o[q] = fast_tanh(acc2[m][q] + bv[q]);
      *(float4v*)(out + (size_t)(m0 + row) * IN_D + col0) = o;
    }
  }
}

// ---------------------------------------------------------------------------
// rec_all: ALL 5 recurrence steps in one kernel. Block = one chain (32 rows).
// xsall writes staged through sA (linear) + coalesced 1KB dump (R18 fix).
// ---------------------------------------------------------------------------
__global__ __launch_bounds__(512) void rec_all_k(
    const unsigned short* __restrict__ Wrec,
    unsigned short* __restrict__ xsall)   // in: xseq rows at t0; out: pred states
{
  __shared__ float xst[32][516];                                        // 64.5 KB
  __shared__ __attribute__((aligned(16))) unsigned short sA[32 * 512];  // 32 KB

  const int tid = threadIdx.x;
  const int chain = blockIdx.x;
  const int t0 = chain * 5;
  const int wave = tid >> 6, lane = tid & 63;
  const int wn = wave;
  const int lrow = lane & 15, lhi = lane >> 4, sw = lrow & 7;

  // coalesced init: xsall[row, t0, :] bf16 -> xst f32
#pragma unroll
  for (int p = 0; p < 4; ++p) {
    int id = (p << 9) + tid;
    int row = id >> 6, c8 = (id & 63) << 3;
    u16x8 v = *(const u16x8*)(xsall + (((size_t)row * T_SZ + t0) << 9) + c8);
#pragma unroll
    for (int e = 0; e < 8; ++e) xst[row][c8 + e] = bf2f(v[e]);
  }
  __syncthreads();

  const unsigned short* bl = Wrec + (lane << 3);
  const int nfb = (wn << 2) << 4;

  for (int s = 0; s < 5; ++s) {
    // stage tanh(xst) -> sA (swizzled)
#pragma unroll
    for (int p = 0; p < 4; ++p) {
      int id = (p << 9) + tid;
      int row = id >> 6, cc = id & 63;
      int gc = (cc & ~7) | ((cc & 7) ^ (row & 7));
      const float* src = &xst[row][gc << 3];
      float4v u0 = *(const float4v*)src;
      float4v u1 = *(const float4v*)(src + 4);
      u16x8 h;
      h[0] = f2bf(fast_tanh(u0[0])); h[1] = f2bf(fast_tanh(u0[1]));
      h[2] = f2bf(fast_tanh(u0[2])); h[3] = f2bf(fast_tanh(u0[3]));
      h[4] = f2bf(fast_tanh(u1[0])); h[5] = f2bf(fast_tanh(u1[1]));
      h[6] = f2bf(fast_tanh(u1[2])); h[7] = f2bf(fast_tanh(u1[3]));
      *(u16x8*)(sA + (row << 9) + (cc << 3)) = h;
    }
    __syncthreads();

    f32x4 acc[2][4];
#pragma unroll
    for (int m = 0; m < 2; ++m)
#pragma unroll
      for (int n = 0; n < 4; ++n) acc[m][n] = (f32x4){0.f, 0.f, 0.f, 0.f};

    bf16x8 b0[4], b1[4];
#pragma unroll
    for (int n = 0; n < 4; ++n)
      b0[n] = *(const bf16x8*)(bl + ((nfb + (n << 4)) << 9));
    for (int kk = 0; kk < 16; kk += 2) {
#pragma unroll
      for (int n = 0; n < 4; ++n)
        b1[n] = *(const bf16x8*)(bl + ((nfb + (n << 4) + kk + 1) << 9));
      {
        const int c = (kk << 2) + lhi;
        const int slot = (c & ~7) | ((c & 7) ^ sw);
        bf16x8 af0 = *(const bf16x8*)(sA + (lrow << 9) + (slot << 3));
        bf16x8 af1 = *(const bf16x8*)(sA + ((16 + lrow) << 9) + (slot << 3));
#pragma unroll
        for (int n = 0; n < 4; ++n) {
          acc[0][n] = MFMA(b0[n], af0, acc[0][n]);
          acc[1][n] = MFMA(b0[n], af1, acc[1][n]);
        }
      }
      if (kk + 2 < 16) {
#pragma unroll
        for (int n = 0; n < 4; ++n)
          b0[n] = *(const bf16x8*)(bl + ((nfb + (n << 4) + kk + 2) << 9));
      }
      {
        const int c = ((kk + 1) << 2) + lhi;
        const int slot = (c & ~7) | ((c & 7) ^ sw);
        bf16x8 af0 = *(const bf16x8*)(sA + (lrow << 9) + (slot << 3));
        bf16x8 af1 = *(const bf16x8*)(sA + ((16 + lrow) << 9) + (slot << 3));
#pragma unroll
        for (int n = 0; n < 4; ++n) {
          acc[0][n] = MFMA(b1[n], af0, acc[0][n]);
          acc[1][n] = MFMA(b1[n], af1, acc[1][n]);
        }
      }
    }
    __syncthreads();   // all k-loop reads of sA complete -> safe to overwrite

    // epilogue: update xst in place + write xnew bf16 into sA (LINEAR)
#pragma unroll
    for (int n = 0; n < 4; ++n) {
      const int col0 = (wn << 6) + n * 16 + (lhi << 2);
#pragma unroll
      for (int m = 0; m < 2; ++m) {
        const int row = m * 16 + lrow;
        float4v x = *(const float4v*)(&xst[row][col0]);
        float4v xn;
        u16x4 h;
#pragma unroll
        for (int q = 0; q < 4; ++q) {
          xn[q] = x[q] + (acc[m][n][q] - x[q]) * INV_TAUX;
          h[q] = f2bf(xn[q]);
        }
        *(float4v*)(&xst[row][col0]) = xn;
        *(u16x4*)(sA + (row << 9) + col0) = h;
      }
    }
    __syncthreads();   // sA fully written by all waves

    // coalesced dump: sA -> xsall[:, t, :] (1KB full lines per wave)
    const int t = t0 + s;
    if (t < T_SZ) {
#pragma unroll
      for (int p = 0; p < 4; ++p) {
        int id = (p << 9) + tid;
        int row = id >> 6, c8 = (id & 63) << 3;
        u16x8 v = *(const u16x8*)(sA + (row << 9) + c8);
        *(u16x8*)(xsall + (((size_t)row * T_SZ + t) << 9) + c8) = v;
      }
    }
    __syncthreads();   // dump reads done before next step's staging overwrites
  }
}

// weight prep into fragment-linear layout:
// flat[((nf*nk+kk)*64+lane)*8+e] = B[nf*16+(lane&15)][kk*32+(lane>>4)*8+e]
__global__ void prep_k(const float* __restrict__ We1, const float* __restrict__ We2,
                       const float* __restrict__ We3, const float* __restrict__ Wd1,
                       const float* __restrict__ Wd2, const float* __restrict__ W,
                       unsigned short* __restrict__ wt) {
  int idx = blockIdx.x * blockDim.x + threadIdx.x;
  if (idx >= 1179648) return;
  unsigned short v;
  if (idx < 65536) {
    int i = idx, lane = (i >> 3) & 63, t2 = i >> 9;
    int kk = t2 & 3, nf = t2 >> 2;
    int n = (nf << 4) + (lane & 15), k = (kk << 5) + ((lane >> 4) << 3) + (i & 7);
    v = f2bf(We1[k * 512 + n]);
  } else if (idx < 327680) {
    int i = idx - 65536, lane = (i >> 3) & 63, t2 = i >> 9;
    int kk = t2 & 15, nf = t2 >> 4;
    int n = (nf << 4) + (lane & 15), k = (kk << 5) + ((lane >> 4) << 3) + (i & 7);
    v = f2bf(We2[k * 512 + n]);
  } else if (idx < 589824) {
    int i = idx - 327680, lane = (i >> 3) & 63, t2 = i >> 9;
    int kk = t2 & 15, nf = t2 >> 4;
    int n = (nf << 4) + (lane & 15), k = (kk << 5) + ((lane >> 4) << 3) + (i & 7);
    v = f2bf(We3[k * 512 + n]);
  } else if (idx < 851968) {
    int i = idx - 589824, lane = (i >> 3) & 63, t2 = i >> 9;
    int kk = t2 & 15, nf = t2 >> 4;
    int n = (nf << 4) + (lane & 15), k = (kk << 5) + ((lane >> 4) << 3) + (i & 7);
    v = f2bf(Wd1[k * 512 + n]);
  } else if (idx < 917504) {
    int i = idx - 851968, lane = (i >> 3) & 63, t2 = i >> 9;
    int kk = t2 & 15, nf = t2 >> 4;
    int n = (nf << 4) + (lane & 15), k = (kk << 5) + ((lane >> 4) << 3) + (i & 7);
    v = f2bf(Wd2[k * 128 + n]);
  } else {
    int i = idx - 917504, lane = (i >> 3) & 63, t2 = i >> 9;
    int kk = t2 & 15, nf = t2 >> 4;
    int n = (nf << 4) + (lane & 15), k = (kk << 5) + ((lane >> 4) << 3) + (i & 7);
    v = f2bf(W[(n << 9) + k]);
  }
  wt[idx] = v;
}

__global__ void sentinel_k(float* out, float v) { out[0] = v; }

extern "C" void kernel_launch(void* const* d_in, const int* in_sizes, int n_in,
                              void* d_out, int out_size, void* d_ws, size_t ws_size,
                              hipStream_t stream) {
  const float* in_seq = (const float*)d_in[0];
  const float* We1 = (const float*)d_in[1];
  const float* be1 = (const float*)d_in[2];
  const float* We2 = (const float*)d_in[3];
  const float* be2 = (const float*)d_in[4];
  const float* We3 = (const float*)d_in[5];
  const float* be3 = (const float*)d_in[6];
  const float* Wd1 = (const float*)d_in[7];
  const float* bd1 = (const float*)d_in[8];
  const float* Wd2 = (const float*)d_in[9];
  const float* bd2 = (const float*)d_in[10];
  const float* W   = (const float*)d_in[11];

  const int NROW = B_SZ * T_SZ;                       // 65536
  const size_t OFF_XSEQ = 0;                          // 67,108,864 B
  const size_t OFF_WT   = (size_t)NROW * HID * 2;     // 67,108,864
  const size_t REQUIRED = OFF_WT + 2359296;           // 69,468,160

  float* outp = (float*)d_out;
  float* outr = outp + (size_t)NROW * IN_D;

  if (ws_size < REQUIRED) {
    sentinel_k<<<1, 1, 0, stream>>>(outp, (float)(ws_size >> 20));
    return;
  }

  char* ws = (char*)d_ws;
  unsigned short* xseq = (unsigned short*)(ws + OFF_XSEQ);  // reused as xsall
  unsigned short* wt   = (unsigned short*)(ws + OFF_WT);
  unsigned short* Wd1t = wt + 589824;
  unsigned short* Wd2t = wt + 851968;
  unsigned short* Wrec = wt + 917504;

  prep_k<<<4608, 256, 0, stream>>>(We1, We2, We3, Wd1, Wd2, W, wt);
  enc5_k<<<1024, 512, 0, stream>>>(in_seq, wt, be1, be2, be3,
                                   Wd1t, Wd2t, bd1, bd2, xseq, outr);
  rec_all_k<<<NCHAIN, 512, 0, stream>>>(Wrec, xseq);
  dec_fused_k<<<512, 1024, 0, stream>>>(xseq, Wd1t, Wd2t, bd1, bd2, outp);
}

// Round 20
// 452.972 us; speedup vs baseline: 1.0435x; 1.0191x over previous
//
#include <hip/hip_runtime.h>
#include <stdint.h>

#define B_SZ  32
#define T_SZ  2048
#define IN_D  128
#define HID   512
#define NCHAIN 410              // ceil(T/5)
#define INV_TAUX 0.005f         // 1/200

typedef __attribute__((ext_vector_type(8))) short bf16x8;
typedef __attribute__((ext_vector_type(4))) float f32x4;
typedef __attribute__((ext_vector_type(4))) float float4v;
typedef __attribute__((ext_vector_type(4))) unsigned short u16x4;
typedef __attribute__((ext_vector_type(8))) unsigned short u16x8;

// Operands SWAPPED: mfma(b, a) => D^T. Lane holds row = frag_m*16 + (lane&15),
// cols = frag_n*16 + (lane>>4)*4 + q (4 consecutive) -> vectorized epilogues.
#define MFMA(b, a, c) __builtin_amdgcn_mfma_f32_16x16x32_bf16((b), (a), (c), 0, 0, 0)

__device__ __forceinline__ unsigned short f2bf(float x) {
  union { float f; unsigned int u; } v; v.f = x;
  unsigned int r = v.u + 0x7FFFu + ((v.u >> 16) & 1u);  // RNE
  return (unsigned short)(r >> 16);
}
__device__ __forceinline__ float bf2f(unsigned short b) {
  union { unsigned int u; float f; } v; v.u = ((unsigned int)b) << 16;
  return v.f;
}
__device__ __forceinline__ float fast_tanh(float x) {
  float ax = fabsf(x);
  float e = __expf(-2.0f * ax);
  float r = (1.0f - e) * __builtin_amdgcn_rcpf(1.0f + e);
  return x < 0.0f ? -r : r;
}
__device__ __forceinline__ void gload_lds16(const void* g, void* l) {
  __builtin_amdgcn_global_load_lds(
      reinterpret_cast<__attribute__((address_space(1))) void*>(reinterpret_cast<uintptr_t>(g)),
      reinterpret_cast<__attribute__((address_space(3))) void*>(reinterpret_cast<uintptr_t>(l)),
      16, 0, 0);
}

// ---------------------------------------------------------------------------
// ROUND-20: rec_all's 253us / FETCH 128MB diagnosed as L2 thrash: Wrec demand
// is 410 blk x 5 steps x 512KB = 1.05GB; the 67MB xsall write stream evicts
// the 0.5MB W between reuses (12% miss -> 128MB HBM re-fetch). Fix: xsall
// dump + init use NON-TEMPORAL stores/loads (bypass L2) so W stays resident.
// enc5/dec/prep byte-identical to R19.
// ---------------------------------------------------------------------------

// ---------------------------------------------------------------------------
// enc5: 3 encoder layers + xseq dump + 2 recon-decoder layers, one kernel.
// 512 thr = 8 waves (1m x 8n), 64 rows/block, LDS 64 KB.
// ---------------------------------------------------------------------------
__global__ __launch_bounds__(512) void enc5_k(
    const float* __restrict__ in_seq,
    const unsigned short* __restrict__ wt,
    const float* __restrict__ be1, const float* __restrict__ be2,
    const float* __restrict__ be3,
    const unsigned short* __restrict__ Wd1t,
    const unsigned short* __restrict__ Wd2t,
    const float* __restrict__ bd1, const float* __restrict__ bd2,
    unsigned short* __restrict__ xseq,
    float* __restrict__ outr)
{
  __shared__ __attribute__((aligned(16))) unsigned short sH[64 * 512];  // 64 KB
  unsigned short* sA = sH;   // alias: input tile (64x128) in sH's head

  const int tid = threadIdx.x;
  const int m0 = blockIdx.x * 64;
  const int wave = tid >> 6, lane = tid & 63;
  const int wn = wave;
  const int lrow = lane & 15, lhi = lane >> 4, sw = lrow & 7;

  // stage input tile f32 -> bf16, chunk-swizzled
#pragma unroll
  for (int p = 0; p < 2; ++p) {
    int id = (p << 9) + tid;
    int row = id >> 4, cc = id & 15;
    const float* src = in_seq + (size_t)(m0 + row) * IN_D + (cc << 3);
    float4v u0 = *(const float4v*)src;
    float4v u1 = *(const float4v*)(src + 4);
    u16x8 h;
    h[0] = f2bf(u0[0]); h[1] = f2bf(u0[1]); h[2] = f2bf(u0[2]); h[3] = f2bf(u0[3]);
    h[4] = f2bf(u1[0]); h[5] = f2bf(u1[1]); h[6] = f2bf(u1[2]); h[7] = f2bf(u1[3]);
    int slot = (cc & 8) | ((cc & 7) ^ (row & 7));
    *(u16x8*)(sA + (row << 7) + (slot << 3)) = h;
  }
  __syncthreads();

  f32x4 acc[4][4];
  const unsigned short* Bts[3] = {wt, wt + 65536, wt + 327680};
  const float* bss[3] = {be1, be2, be3};

  // ---- 3 encoder layers (in-place in sH) ----
  for (int l = 0; l < 3; ++l) {
    const int lstr = (l == 0) ? 128 : 512;
    const int nk = (l == 0) ? 4 : 16;
    const unsigned short* bl = Bts[l] + (lane << 3);
    const int nfb = (wn << 2) * nk;
    const float* bias = bss[l];

#pragma unroll
    for (int m = 0; m < 4; ++m)
#pragma unroll
      for (int n = 0; n < 4; ++n) acc[m][n] = (f32x4){0.f, 0.f, 0.f, 0.f};

    bf16x8 b0[4], b1[4];
#pragma unroll
    for (int n = 0; n < 4; ++n)
      b0[n] = *(const bf16x8*)(bl + ((nfb + n * nk) << 9));

    for (int kk = 0; kk < nk; kk += 2) {
#pragma unroll
      for (int n = 0; n < 4; ++n)
        b1[n] = *(const bf16x8*)(bl + ((nfb + n * nk + kk + 1) << 9));
      {
        const int c = (kk << 2) + lhi;
        const int slot = (c & ~7) | ((c & 7) ^ sw);
        bf16x8 af[4];
#pragma unroll
        for (int m = 0; m < 4; ++m)
          af[m] = *(const bf16x8*)(sH + (m * 16 + lrow) * lstr + (slot << 3));
#pragma unroll
        for (int n = 0; n < 4; ++n)
#pragma unroll
          for (int m = 0; m < 4; ++m)
            acc[m][n] = MFMA(b0[n], af[m], acc[m][n]);
      }
      if (kk + 2 < nk) {
#pragma unroll
        for (int n = 0; n < 4; ++n)
          b0[n] = *(const bf16x8*)(bl + ((nfb + n * nk + kk + 2) << 9));
      }
      {
        const int c = ((kk + 1) << 2) + lhi;
        const int slot = (c & ~7) | ((c & 7) ^ sw);
        bf16x8 af[4];
#pragma unroll
        for (int m = 0; m < 4; ++m)
          af[m] = *(const bf16x8*)(sH + (m * 16 + lrow) * lstr + (slot << 3));
#pragma unroll
        for (int n = 0; n < 4; ++n)
#pragma unroll
          for (int m = 0; m < 4; ++m)
            acc[m][n] = MFMA(b1[n], af[m], acc[m][n]);
      }
    }
    __syncthreads();
    // epilogue: acc[m][n][q] = D[row=m*16+lrow][col=wn*64+n*16+lhi*4+q]
#pragma unroll
    for (int n = 0; n < 4; ++n) {
      const int col0 = (wn << 6) + n * 16 + (lhi << 2);
      const float4v bv = *(const float4v*)(bias + col0);
      const int c2 = col0 >> 3;
#pragma unroll
      for (int m = 0; m < 4; ++m) {
        const int row = m * 16 + lrow;
        const int slot2 = (c2 & ~7) | ((c2 & 7) ^ (row & 7));
        u16x4 h;
#pragma unroll
        for (int q = 0; q < 4; ++q) h[q] = f2bf(fast_tanh(acc[m][n][q] + bv[q]));
        *(u16x4*)(sH + (row << 9) + (slot2 << 3) + (col0 & 7)) = h;
      }
    }
    __syncthreads();
  }

  // ---- dump xseq (coalesced un-swizzle; read-only on sH) ----
#pragma unroll
  for (int p = 0; p < 8; ++p) {
    int id = (p << 9) + tid;
    int row = id >> 6, cc = id & 63;
    int slot = (cc & ~7) | ((cc & 7) ^ (row & 7));
    u16x8 v = *(const u16x8*)(sH + (row << 9) + (slot << 3));
    *(u16x8*)(xseq + ((size_t)(m0 + row) << 9) + (cc << 3)) = v;
  }

  // ---- recon decoder layer 1 (reads sH-as-X, writes sH-as-d1 in place) ----
#pragma unroll
  for (int m = 0; m < 4; ++m)
#pragma unroll
    for (int n = 0; n < 4; ++n) acc[m][n] = (f32x4){0.f, 0.f, 0.f, 0.f};

  {
    const unsigned short* bl = Wd1t + (lane << 3);
    const int nfb = (wn << 2) << 4;
    bf16x8 b0[4], b1[4];
#pragma unroll
    for (int n = 0; n < 4; ++n)
      b0[n] = *(const bf16x8*)(bl + ((nfb + (n << 4)) << 9));
    for (int kk = 0; kk < 16; kk += 2) {
#pragma unroll
      for (int n = 0; n < 4; ++n)
        b1[n] = *(const bf16x8*)(bl + ((nfb + (n << 4) + kk + 1) << 9));
      {
        const int c = (kk << 2) + lhi;
        const int slot = (c & ~7) | ((c & 7) ^ sw);
        bf16x8 af[4];
#pragma unroll
        for (int m = 0; m < 4; ++m)
          af[m] = *(const bf16x8*)(sH + ((m * 16 + lrow) << 9) + (slot << 3));
#pragma unroll
        for (int n = 0; n < 4; ++n)
#pragma unroll
          for (int m = 0; m < 4; ++m)
            acc[m][n] = MFMA(b0[n], af[m], acc[m][n]);
      }
      if (kk + 2 < 16) {
#pragma unroll
        for (int n = 0; n < 4; ++n)
          b0[n] = *(const bf16x8*)(bl + ((nfb + (n << 4) + kk + 2) << 9));
      }
      {
        const int c = ((kk + 1) << 2) + lhi;
        const int slot = (c & ~7) | ((c & 7) ^ sw);
        bf16x8 af[4];
#pragma unroll
        for (int m = 0; m < 4; ++m)
          af[m] = *(const bf16x8*)(sH + ((m * 16 + lrow) << 9) + (slot << 3));
#pragma unroll
        for (int n = 0; n < 4; ++n)
#pragma unroll
          for (int m = 0; m < 4; ++m)
            acc[m][n] = MFMA(b1[n], af[m], acc[m][n]);
      }
    }
  }
  __syncthreads();   // all sH(X) reads + dump reads done -> overwrite as d1
#pragma unroll
  for (int n = 0; n < 4; ++n) {
    const int col0 = (wn << 6) + n * 16 + (lhi << 2);
    const float4v bv = *(const float4v*)(bd1 + col0);
    const int c2 = col0 >> 3;
#pragma unroll
    for (int m = 0; m < 4; ++m) {
      const int row = m * 16 + lrow;
      const int slot2 = (c2 & ~7) | ((c2 & 7) ^ (row & 7));
      u16x4 h;
#pragma unroll
      for (int q = 0; q < 4; ++q) h[q] = f2bf(fast_tanh(acc[m][n][q] + bv[q]));
      *(u16x4*)(sH + (row << 9) + (slot2 << 3) + (col0 & 7)) = h;
    }
  }
  __syncthreads();

  // ---- recon decoder layer 2: N=128, wave owns one 16-col frag ----
  f32x4 acc2[4];
#pragma unroll
  for (int m = 0; m < 4; ++m) acc2[m] = (f32x4){0.f, 0.f, 0.f, 0.f};

  {
    const unsigned short* bl = Wd2t + (lane << 3);
    const int nfb = wn << 4;
    bf16x8 c0, c1;
    c0 = *(const bf16x8*)(bl + ((nfb + 0) << 9));
    for (int kk = 0; kk < 16; kk += 2) {
      c1 = *(const bf16x8*)(bl + ((nfb + kk + 1) << 9));
      {
        const int c = (kk << 2) + lhi;
        const int slot = (c & ~7) | ((c & 7) ^ sw);
#pragma unroll
        for (int m = 0; m < 4; ++m) {
          bf16x8 af = *(const bf16x8*)(sH + ((m * 16 + lrow) << 9) + (slot << 3));
          acc2[m] = MFMA(c0, af, acc2[m]);
        }
      }
      if (kk + 2 < 16)
        c0 = *(const bf16x8*)(bl + ((nfb + kk + 2) << 9));
      {
        const int c = ((kk + 1) << 2) + lhi;
        const int slot = (c & ~7) | ((c & 7) ^ sw);
#pragma unroll
        for (int m = 0; m < 4; ++m) {
          bf16x8 af = *(const bf16x8*)(sH + ((m * 16 + lrow) << 9) + (slot << 3));
          acc2[m] = MFMA(c1, af, acc2[m]);
        }
      }
    }
  }
  {
    const int col0 = (wn << 4) + (lhi << 2);
    const float4v bv = *(const float4v*)(bd2 + col0);
#pragma unroll
    for (int m = 0; m < 4; ++m) {
      const int row = m * 16 + lrow;
      float4v o;
#pragma unroll
      for (int q = 0; q < 4; ++q) o[q] = fast_tanh(acc2[m][q] + bv[q]);
      *(float4v*)(outr + (size_t)(m0 + row) * IN_D + col0) = o;
    }
  }
}

// ---------------------------------------------------------------------------
// Fused 2-layer decoder (pred pass). 1024 thr = 16 waves (2wm x 8wn),
// 128 rows/block, MF=4.
// ---------------------------------------------------------------------------
__global__ __launch_bounds__(1024) void dec_fused_k(
    const unsigned short* __restrict__ X,
    const unsigned short* __restrict__ Wd1t,
    const unsigned short* __restrict__ Wd2t,
    const float* __restrict__ bd1, const float* __restrict__ bd2,
    float* __restrict__ out)
{
  __shared__ __attribute__((aligned(16))) unsigned short sH[128 * 512];  // 128 KB
  unsigned short* sX = sH;

  const int tid = threadIdx.x;
  const int m0 = blockIdx.x * 128;
  const int wave = tid >> 6, lane = tid & 63;
  const int wm = wave >> 3, wn = wave & 7;
  const int rb = wm << 6;
  const int lrow = lane & 15, lhi = lane >> 4, sw = lrow & 7;

  char* lX = (char*)sX + tid * 16;
#pragma unroll
  for (int p = 0; p < 8; ++p) {
    int id = (p << 10) + tid;
    int row = id >> 6, cc = id & 63;
    int gcc = (cc & ~7) | ((cc & 7) ^ (row & 7));
    gload_lds16(X + ((size_t)(m0 + row) << 9) + (gcc << 3), lX + (p << 14));
  }
  __syncthreads();

  f32x4 acc[4][4];
#pragma unroll
  for (int m = 0; m < 4; ++m)
#pragma unroll
    for (int n = 0; n < 4; ++n) acc[m][n] = (f32x4){0.f, 0.f, 0.f, 0.f};

  {
    const unsigned short* bl = Wd1t + (lane << 3);
    const int nfb = (wn << 2) << 4;
    bf16x8 b0[4], b1[4];
#pragma unroll
    for (int n = 0; n < 4; ++n)
      b0[n] = *(const bf16x8*)(bl + ((nfb + (n << 4)) << 9));
    for (int kk = 0; kk < 16; kk += 2) {
#pragma unroll
      for (int n = 0; n < 4; ++n)
        b1[n] = *(const bf16x8*)(bl + ((nfb + (n << 4) + kk + 1) << 9));
      {
        const int c = (kk << 2) + lhi;
        const int slot = (c & ~7) | ((c & 7) ^ sw);
        bf16x8 af[4];
#pragma unroll
        for (int m = 0; m < 4; ++m)
          af[m] = *(const bf16x8*)(sX + ((rb + m * 16 + lrow) << 9) + (slot << 3));
#pragma unroll
        for (int n = 0; n < 4; ++n)
#pragma unroll
          for (int m = 0; m < 4; ++m)
            acc[m][n] = MFMA(b0[n], af[m], acc[m][n]);
      }
      if (kk + 2 < 16) {
#pragma unroll
        for (int n = 0; n < 4; ++n)
          b0[n] = *(const bf16x8*)(bl + ((nfb + (n << 4) + kk + 2) << 9));
      }
      {
        const int c = ((kk + 1) << 2) + lhi;
        const int slot = (c & ~7) | ((c & 7) ^ sw);
        bf16x8 af[4];
#pragma unroll
        for (int m = 0; m < 4; ++m)
          af[m] = *(const bf16x8*)(sX + ((rb + m * 16 + lrow) << 9) + (slot << 3));
#pragma unroll
        for (int n = 0; n < 4; ++n)
#pragma unroll
          for (int m = 0; m < 4; ++m)
            acc[m][n] = MFMA(b1[n], af[m], acc[m][n]);
      }
    }
  }
  __syncthreads();
#pragma unroll
  for (int n = 0; n < 4; ++n) {
    const int col0 = (wn << 6) + n * 16 + (lhi << 2);
    const float4v bv = *(const float4v*)(bd1 + col0);
    const int c2 = col0 >> 3;
#pragma unroll
    for (int m = 0; m < 4; ++m) {
      const int row = rb + m * 16 + lrow;
      const int slot2 = (c2 & ~7) | ((c2 & 7) ^ (row & 7));
      u16x4 h;
#pragma unroll
      for (int q = 0; q < 4; ++q) h[q] = f2bf(fast_tanh(acc[m][n][q] + bv[q]));
      *(u16x4*)(sH + (row << 9) + (slot2 << 3) + (col0 & 7)) = h;
    }
  }
  __syncthreads();

  f32x4 acc2[4];
#pragma unroll
  for (int m = 0; m < 4; ++m) acc2[m] = (f32x4){0.f, 0.f, 0.f, 0.f};

  {
    const unsigned short* bl = Wd2t + (lane << 3);
    const int nfb = wn << 4;
    bf16x8 c0, c1;
    c0 = *(const bf16x8*)(bl + ((nfb + 0) << 9));
    for (int kk = 0; kk < 16; kk += 2) {
      c1 = *(const bf16x8*)(bl + ((nfb + kk + 1) << 9));
      {
        const int c = (kk << 2) + lhi;
        const int slot = (c & ~7) | ((c & 7) ^ sw);
#pragma unroll
        for (int m = 0; m < 4; ++m) {
          bf16x8 af = *(const bf16x8*)(sH + ((rb + m * 16 + lrow) << 9) + (slot << 3));
          acc2[m] = MFMA(c0, af, acc2[m]);
        }
      }
      if (kk + 2 < 16)
        c0 = *(const bf16x8*)(bl + ((nfb + kk + 2) << 9));
      {
        const int c = ((kk + 1) << 2) + lhi;
        const int slot = (c & ~7) | ((c & 7) ^ sw);
#pragma unroll
        for (int m = 0; m < 4; ++m) {
          bf16x8 af = *(const bf16x8*)(sH + ((rb + m * 16 + lrow) << 9) + (slot << 3));
          acc2[m] = MFMA(c1, af, acc2[m]);
        }
      }
    }
  }
  {
    const int col0 = (wn << 4) + (lhi << 2);
    const float4v bv = *(const float4v*)(bd2 + col0);
#pragma unroll
    for (int m = 0; m < 4; ++m) {
      const int row = rb + m * 16 + lrow;
      float4v o;
#pragma unroll
      for (int q = 0; q < 4; ++q) o[q] = fast_tanh(acc2[m][q] + bv[q]);
      *(float4v*)(out + (size_t)(m0 + row) * IN_D + col0) = o;
    }
  }
}

// ---------------------------------------------------------------------------
// rec_all: ALL 5 recurrence steps in one kernel. Block = one chain (32 rows).
// xsall traffic is NON-TEMPORAL (bypass L2) so Wrec stays L2-resident.
// ---------------------------------------------------------------------------
__global__ __launch_bounds__(512) void rec_all_k(
    const unsigned short* __restrict__ Wrec,
    unsigned short* __restrict__ xsall)   // in: xseq rows at t0; out: pred states
{
  __shared__ float xst[32][516];                                        // 64.5 KB
  __shared__ __attribute__((aligned(16))) unsigned short sA[32 * 512];  // 32 KB

  const int tid = threadIdx.x;
  const int chain = blockIdx.x;
  const int t0 = chain * 5;
  const int wave = tid >> 6, lane = tid & 63;
  const int wn = wave;
  const int lrow = lane & 15, lhi = lane >> 4, sw = lrow & 7;

  // coalesced init: xsall[row, t0, :] bf16 -> xst f32 (non-temporal read)
#pragma unroll
  for (int p = 0; p < 4; ++p) {
    int id = (p << 9) + tid;
    int row = id >> 6, c8 = (id & 63) << 3;
    u16x8 v = __builtin_nontemporal_load(
        (const u16x8*)(xsall + (((size_t)row * T_SZ + t0) << 9) + c8));
#pragma unroll
    for (int e = 0; e < 8; ++e) xst[row][c8 + e] = bf2f(v[e]);
  }
  __syncthreads();

  const unsigned short* bl = Wrec + (lane << 3);
  const int nfb = (wn << 2) << 4;

  for (int s = 0; s < 5; ++s) {
    // stage tanh(xst) -> sA (swizzled)
#pragma unroll
    for (int p = 0; p < 4; ++p) {
      int id = (p << 9) + tid;
      int row = id >> 6, cc = id & 63;
      int gc = (cc & ~7) | ((cc & 7) ^ (row & 7));
      const float* src = &xst[row][gc << 3];
      float4v u0 = *(const float4v*)src;
      float4v u1 = *(const float4v*)(src + 4);
      u16x8 h;
      h[0] = f2bf(fast_tanh(u0[0])); h[1] = f2bf(fast_tanh(u0[1]));
      h[2] = f2bf(fast_tanh(u0[2])); h[3] = f2bf(fast_tanh(u0[3]));
      h[4] = f2bf(fast_tanh(u1[0])); h[5] = f2bf(fast_tanh(u1[1]));
      h[6] = f2bf(fast_tanh(u1[2])); h[7] = f2bf(fast_tanh(u1[3]));
      *(u16x8*)(sA + (row << 9) + (cc << 3)) = h;
    }
    __syncthreads();

    f32x4 acc[2][4];
#pragma unroll
    for (int m = 0; m < 2; ++m)
#pragma unroll
      for (int n = 0; n < 4; ++n) acc[m][n] = (f32x4){0.f, 0.f, 0.f, 0.f};

    bf16x8 b0[4], b1[4];
#pragma unroll
    for (int n = 0; n < 4; ++n)
      b0[n] = *(const bf16x8*)(bl + ((nfb + (n << 4)) << 9));
    for (int kk = 0; kk < 16; kk += 2) {
#pragma unroll
      for (int n = 0; n < 4; ++n)
        b1[n] = *(const bf16x8*)(bl + ((nfb + (n << 4) + kk + 1) << 9));
      {
        const int c = (kk << 2) + lhi;
        const int slot = (c & ~7) | ((c & 7) ^ sw);
        bf16x8 af0 = *(const bf16x8*)(sA + (lrow << 9) + (slot << 3));
        bf16x8 af1 = *(const bf16x8*)(sA + ((16 + lrow) << 9) + (slot << 3));
#pragma unroll
        for (int n = 0; n < 4; ++n) {
          acc[0][n] = MFMA(b0[n], af0, acc[0][n]);
          acc[1][n] = MFMA(b0[n], af1, acc[1][n]);
        }
      }
      if (kk + 2 < 16) {
#pragma unroll
        for (int n = 0; n < 4; ++n)
          b0[n] = *(const bf16x8*)(bl + ((nfb + (n << 4) + kk + 2) << 9));
      }
      {
        const int c = ((kk + 1) << 2) + lhi;
        const int slot = (c & ~7) | ((c & 7) ^ sw);
        bf16x8 af0 = *(const bf16x8*)(sA + (lrow << 9) + (slot << 3));
        bf16x8 af1 = *(const bf16x8*)(sA + ((16 + lrow) << 9) + (slot << 3));
#pragma unroll
        for (int n = 0; n < 4; ++n) {
          acc[0][n] = MFMA(b1[n], af0, acc[0][n]);
          acc[1][n] = MFMA(b1[n], af1, acc[1][n]);
        }
      }
    }
    __syncthreads();   // all k-loop reads of sA complete -> safe to overwrite

    // epilogue: update xst in place + write xnew bf16 into sA (LINEAR)
#pragma unroll
    for (int n = 0; n < 4; ++n) {
      const int col0 = (wn << 6) + n * 16 + (lhi << 2);
#pragma unroll
      for (int m = 0; m < 2; ++m) {
        const int row = m * 16 + lrow;
        float4v x = *(const float4v*)(&xst[row][col0]);
        float4v xn;
        u16x4 h;
#pragma unroll
        for (int q = 0; q < 4; ++q) {
          xn[q] = x[q] + (acc[m][n][q] - x[q]) * INV_TAUX;
          h[q] = f2bf(xn[q]);
        }
        *(float4v*)(&xst[row][col0]) = xn;
        *(u16x4*)(sA + (row << 9) + col0) = h;
      }
    }
    __syncthreads();   // sA fully written by all waves

    // non-temporal coalesced dump: sA -> xsall[:, t, :] (bypass L2)
    const int t = t0 + s;
    if (t < T_SZ) {
#pragma unroll
      for (int p = 0; p < 4; ++p) {
        int id = (p << 9) + tid;
        int row = id >> 6, c8 = (id & 63) << 3;
        u16x8 v = *(const u16x8*)(sA + (row << 9) + c8);
        __builtin_nontemporal_store(
            v, (u16x8*)(xsall + (((size_t)row * T_SZ + t) << 9) + c8));
      }
    }
    __syncthreads();   // dump reads done before next step's staging overwrites
  }
}

// weight prep into fragment-linear layout:
// flat[((nf*nk+kk)*64+lane)*8+e] = B[nf*16+(lane&15)][kk*32+(lane>>4)*8+e]
__global__ void prep_k(const float* __restrict__ We1, const float* __restrict__ We2,
                       const float* __restrict__ We3, const float* __restrict__ Wd1,
                       const float* __restrict__ Wd2, const float* __restrict__ W,
                       unsigned short* __restrict__ wt) {
  int idx = blockIdx.x * blockDim.x + threadIdx.x;
  if (idx >= 1179648) return;
  unsigned short v;
  if (idx < 65536) {
    int i = idx, lane = (i >> 3) & 63, t2 = i >> 9;
    int kk = t2 & 3, nf = t2 >> 2;
    int n = (nf << 4) + (lane & 15), k = (kk << 5) + ((lane >> 4) << 3) + (i & 7);
    v = f2bf(We1[k * 512 + n]);
  } else if (idx < 327680) {
    int i = idx - 65536, lane = (i >> 3) & 63, t2 = i >> 9;
    int kk = t2 & 15, nf = t2 >> 4;
    int n = (nf << 4) + (lane & 15), k = (kk << 5) + ((lane >> 4) << 3) + (i & 7);
    v = f2bf(We2[k * 512 + n]);
  } else if (idx < 589824) {
    int i = idx - 327680, lane = (i >> 3) & 63, t2 = i >> 9;
    int kk = t2 & 15, nf = t2 >> 4;
    int n = (nf << 4) + (lane & 15), k = (kk << 5) + ((lane >> 4) << 3) + (i & 7);
    v = f2bf(We3[k * 512 + n]);
  } else if (idx < 851968) {
    int i = idx - 589824, lane = (i >> 3) & 63, t2 = i >> 9;
    int kk = t2 & 15, nf = t2 >> 4;
    int n = (nf << 4) + (lane & 15), k = (kk << 5) + ((lane >> 4) << 3) + (i & 7);
    v = f2bf(Wd1[k * 512 + n]);
  } else if (idx < 917504) {
    int i = idx - 851968, lane = (i >> 3) & 63, t2 = i >> 9;
    int kk = t2 & 15, nf = t2 >> 4;
    int n = (nf << 4) + (lane & 15), k = (kk << 5) + ((lane >> 4) << 3) + (i & 7);
    v = f2bf(Wd2[k * 128 + n]);
  } else {
    int i = idx - 917504, lane = (i >> 3) & 63, t2 = i >> 9;
    int kk = t2 & 15, nf = t2 >> 4;
    int n = (nf << 4) + (lane & 15), k = (kk << 5) + ((lane >> 4) << 3) + (i & 7);
    v = f2bf(W[(n << 9) + k]);
  }
  wt[idx] = v;
}

__global__ void sentinel_k(float* out, float v) { out[0] = v; }

extern "C" void kernel_launch(void* const* d_in, const int* in_sizes, int n_in,
                              void* d_out, int out_size, void* d_ws, size_t ws_size,
                              hipStream_t stream) {
  const float* in_seq = (const float*)d_in[0];
  const float* We1 = (const float*)d_in[1];
  const float* be1 = (const float*)d_in[2];
  const float* We2 = (const float*)d_in[3];
  const float* be2 = (const float*)d_in[4];
  const float* We3 = (const float*)d_in[5];
  const float* be3 = (const float*)d_in[6];
  const float* Wd1 = (const float*)d_in[7];
  const float* bd1 = (const float*)d_in[8];
  const float* Wd2 = (const float*)d_in[9];
  const float* bd2 = (const float*)d_in[10];
  const float* W   = (const float*)d_in[11];

  const int NROW = B_SZ * T_SZ;                       // 65536
  const size_t OFF_XSEQ = 0;                          // 67,108,864 B
  const size_t OFF_WT   = (size_t)NROW * HID * 2;     // 67,108,864
  const size_t REQUIRED = OFF_WT + 2359296;           // 69,468,160

  float* outp = (float*)d_out;
  float* outr = outp + (size_t)NROW * IN_D;

  if (ws_size < REQUIRED) {
    sentinel_k<<<1, 1, 0, stream>>>(outp, (float)(ws_size >> 20));
    return;
  }

  char* ws = (char*)d_ws;
  unsigned short* xseq = (unsigned short*)(ws + OFF_XSEQ);  // reused as xsall
  unsigned short* wt   = (unsigned short*)(ws + OFF_WT);
  unsigned short* Wd1t = wt + 589824;
  unsigned short* Wd2t = wt + 851968;
  unsigned short* Wrec = wt + 917504;

  prep_k<<<4608, 256, 0, stream>>>(We1, We2, We3, Wd1, Wd2, W, wt);
  enc5_k<<<1024, 512, 0, stream>>>(in_seq, wt, be1, be2, be3,
                                   Wd1t, Wd2t, bd1, bd2, xseq, outr);
  rec_all_k<<<NCHAIN, 512, 0, stream>>>(Wrec, xseq);
  dec_fused_k<<<512, 1024, 0, stream>>>(xseq, Wd1t, Wd2t, bd1, bd2, outp);
}

// Round 21
// 434.360 us; speedup vs baseline: 1.0882x; 1.0428x over previous
//
#include <hip/hip_runtime.h>
#include <stdint.h>

#define B_SZ  32
#define T_SZ  2048
#define IN_D  128
#define HID   512
#define NCHAIN 410              // ceil(T/5)
#define INV_TAUX 0.005f         // 1/200

typedef __attribute__((ext_vector_type(8))) short bf16x8;
typedef __attribute__((ext_vector_type(4))) float f32x4;
typedef __attribute__((ext_vector_type(4))) float float4v;
typedef __attribute__((ext_vector_type(4))) unsigned short u16x4;
typedef __attribute__((ext_vector_type(8))) unsigned short u16x8;

// Operands SWAPPED: mfma(b, a) => D^T. Lane holds row = frag_m*16 + (lane&15),
// cols = frag_n*16 + (lane>>4)*4 + q (4 consecutive) -> vectorized epilogues.
#define MFMA(b, a, c) __builtin_amdgcn_mfma_f32_16x16x32_bf16((b), (a), (c), 0, 0, 0)

__device__ __forceinline__ unsigned short f2bf(float x) {
  union { float f; unsigned int u; } v; v.f = x;
  unsigned int r = v.u + 0x7FFFu + ((v.u >> 16) & 1u);  // RNE
  return (unsigned short)(r >> 16);
}
__device__ __forceinline__ float bf2f(unsigned short b) {
  union { unsigned int u; float f; } v; v.u = ((unsigned int)b) << 16;
  return v.f;
}
__device__ __forceinline__ float fast_tanh(float x) {
  float ax = fabsf(x);
  float e = __expf(-2.0f * ax);
  float r = (1.0f - e) * __builtin_amdgcn_rcpf(1.0f + e);
  return x < 0.0f ? -r : r;
}
__device__ __forceinline__ void gload_lds16(const void* g, void* l) {
  __builtin_amdgcn_global_load_lds(
      reinterpret_cast<__attribute__((address_space(1))) void*>(reinterpret_cast<uintptr_t>(g)),
      reinterpret_cast<__attribute__((address_space(3))) void*>(reinterpret_cast<uintptr_t>(l)),
      16, 0, 0);
}

// ---------------------------------------------------------------------------
// ROUND-21 (final assembly): R16's exact config (best measured total, 415.8us:
// enc5 = 1024thr 2wm x 8wn MF=4 128-row; dec = 1024thr 128-row) + R20's
// NT-staged rec_all (removes the 253us L2-thrash signature R19 exposed).
// ---------------------------------------------------------------------------

// ---------------------------------------------------------------------------
// enc5: 3 encoder layers + xseq dump + 2 recon-decoder layers, one kernel.
// 1024 thr = 16 waves (2 wm x 8 wn), 128 rows/block, LDS 128 KB.
// ---------------------------------------------------------------------------
__global__ __launch_bounds__(1024) void enc5_k(
    const float* __restrict__ in_seq,
    const unsigned short* __restrict__ wt,
    const float* __restrict__ be1, const float* __restrict__ be2,
    const float* __restrict__ be3,
    const unsigned short* __restrict__ Wd1t,
    const unsigned short* __restrict__ Wd2t,
    const float* __restrict__ bd1, const float* __restrict__ bd2,
    unsigned short* __restrict__ xseq,
    float* __restrict__ outr)
{
  __shared__ __attribute__((aligned(16))) unsigned short sH[128 * 512];  // 128 KB
  unsigned short* sA = sH;   // alias: input tile (128x128) in sH's head

  const int tid = threadIdx.x;
  const int m0 = blockIdx.x * 128;
  const int wave = tid >> 6, lane = tid & 63;
  const int wm = wave >> 3, wn = wave & 7;
  const int rb = wm << 6;                    // wave's row base (0 or 64)
  const int lrow = lane & 15, lhi = lane >> 4, sw = lrow & 7;

  // stage input tile f32 -> bf16, chunk-swizzled (128 rows x 16 chunks)
#pragma unroll
  for (int p = 0; p < 2; ++p) {
    int id = (p << 10) + tid;
    int row = id >> 4, cc = id & 15;
    const float* src = in_seq + (size_t)(m0 + row) * IN_D + (cc << 3);
    float4v u0 = *(const float4v*)src;
    float4v u1 = *(const float4v*)(src + 4);
    u16x8 h;
    h[0] = f2bf(u0[0]); h[1] = f2bf(u0[1]); h[2] = f2bf(u0[2]); h[3] = f2bf(u0[3]);
    h[4] = f2bf(u1[0]); h[5] = f2bf(u1[1]); h[6] = f2bf(u1[2]); h[7] = f2bf(u1[3]);
    int slot = (cc & 8) | ((cc & 7) ^ (row & 7));
    *(u16x8*)(sA + (row << 7) + (slot << 3)) = h;
  }
  __syncthreads();

  f32x4 acc[4][4];
  const unsigned short* Bts[3] = {wt, wt + 65536, wt + 327680};
  const float* bss[3] = {be1, be2, be3};

  // ---- 3 encoder layers (in-place in sH) ----
  for (int l = 0; l < 3; ++l) {
    const int lstr = (l == 0) ? 128 : 512;
    const int nk = (l == 0) ? 4 : 16;
    const unsigned short* bl = Bts[l] + (lane << 3);
    const int nfb = (wn << 2) * nk;
    const float* bias = bss[l];

#pragma unroll
    for (int m = 0; m < 4; ++m)
#pragma unroll
      for (int n = 0; n < 4; ++n) acc[m][n] = (f32x4){0.f, 0.f, 0.f, 0.f};

    bf16x8 b0[4], b1[4];
#pragma unroll
    for (int n = 0; n < 4; ++n)
      b0[n] = *(const bf16x8*)(bl + ((nfb + n * nk) << 9));

    for (int kk = 0; kk < nk; kk += 2) {
#pragma unroll
      for (int n = 0; n < 4; ++n)
        b1[n] = *(const bf16x8*)(bl + ((nfb + n * nk + kk + 1) << 9));
      {
        const int c = (kk << 2) + lhi;
        const int slot = (c & ~7) | ((c & 7) ^ sw);
        bf16x8 af[4];
#pragma unroll
        for (int m = 0; m < 4; ++m)
          af[m] = *(const bf16x8*)(sH + (rb + m * 16 + lrow) * lstr + (slot << 3));
#pragma unroll
        for (int n = 0; n < 4; ++n)
#pragma unroll
          for (int m = 0; m < 4; ++m)
            acc[m][n] = MFMA(b0[n], af[m], acc[m][n]);
      }
      if (kk + 2 < nk) {
#pragma unroll
        for (int n = 0; n < 4; ++n)
          b0[n] = *(const bf16x8*)(bl + ((nfb + n * nk + kk + 2) << 9));
      }
      {
        const int c = ((kk + 1) << 2) + lhi;
        const int slot = (c & ~7) | ((c & 7) ^ sw);
        bf16x8 af[4];
#pragma unroll
        for (int m = 0; m < 4; ++m)
          af[m] = *(const bf16x8*)(sH + (rb + m * 16 + lrow) * lstr + (slot << 3));
#pragma unroll
        for (int n = 0; n < 4; ++n)
#pragma unroll
          for (int m = 0; m < 4; ++m)
            acc[m][n] = MFMA(b1[n], af[m], acc[m][n]);
      }
    }
    __syncthreads();
    // epilogue: acc[m][n][q] = D[row=rb+m*16+lrow][col=wn*64+n*16+lhi*4+q]
#pragma unroll
    for (int n = 0; n < 4; ++n) {
      const int col0 = (wn << 6) + n * 16 + (lhi << 2);
      const float4v bv = *(const float4v*)(bias + col0);
      const int c2 = col0 >> 3;
#pragma unroll
      for (int m = 0; m < 4; ++m) {
        const int row = rb + m * 16 + lrow;
        const int slot2 = (c2 & ~7) | ((c2 & 7) ^ (row & 7));
        u16x4 h;
#pragma unroll
        for (int q = 0; q < 4; ++q) h[q] = f2bf(fast_tanh(acc[m][n][q] + bv[q]));
        *(u16x4*)(sH + (row << 9) + (slot2 << 3) + (col0 & 7)) = h;
      }
    }
    __syncthreads();
  }

  // ---- dump xseq (coalesced un-swizzle; read-only on sH) ----
#pragma unroll
  for (int p = 0; p < 8; ++p) {
    int id = (p << 10) + tid;
    int row = id >> 6, cc = id & 63;
    int slot = (cc & ~7) | ((cc & 7) ^ (row & 7));
    u16x8 v = *(const u16x8*)(sH + (row << 9) + (slot << 3));
    *(u16x8*)(xseq + ((size_t)(m0 + row) << 9) + (cc << 3)) = v;
  }

  // ---- recon decoder layer 1 (reads sH-as-X, writes sH-as-d1 in place) ----
#pragma unroll
  for (int m = 0; m < 4; ++m)
#pragma unroll
    for (int n = 0; n < 4; ++n) acc[m][n] = (f32x4){0.f, 0.f, 0.f, 0.f};

  {
    const unsigned short* bl = Wd1t + (lane << 3);
    const int nfb = (wn << 2) << 4;
    bf16x8 b0[4], b1[4];
#pragma unroll
    for (int n = 0; n < 4; ++n)
      b0[n] = *(const bf16x8*)(bl + ((nfb + (n << 4)) << 9));
    for (int kk = 0; kk < 16; kk += 2) {
#pragma unroll
      for (int n = 0; n < 4; ++n)
        b1[n] = *(const bf16x8*)(bl + ((nfb + (n << 4) + kk + 1) << 9));
      {
        const int c = (kk << 2) + lhi;
        const int slot = (c & ~7) | ((c & 7) ^ sw);
        bf16x8 af[4];
#pragma unroll
        for (int m = 0; m < 4; ++m)
          af[m] = *(const bf16x8*)(sH + ((rb + m * 16 + lrow) << 9) + (slot << 3));
#pragma unroll
        for (int n = 0; n < 4; ++n)
#pragma unroll
          for (int m = 0; m < 4; ++m)
            acc[m][n] = MFMA(b0[n], af[m], acc[m][n]);
      }
      if (kk + 2 < 16) {
#pragma unroll
        for (int n = 0; n < 4; ++n)
          b0[n] = *(const bf16x8*)(bl + ((nfb + (n << 4) + kk + 2) << 9));
      }
      {
        const int c = ((kk + 1) << 2) + lhi;
        const int slot = (c & ~7) | ((c & 7) ^ sw);
        bf16x8 af[4];
#pragma unroll
        for (int m = 0; m < 4; ++m)
          af[m] = *(const bf16x8*)(sH + ((rb + m * 16 + lrow) << 9) + (slot << 3));
#pragma unroll
        for (int n = 0; n < 4; ++n)
#pragma unroll
          for (int m = 0; m < 4; ++m)
            acc[m][n] = MFMA(b1[n], af[m], acc[m][n]);
      }
    }
  }
  __syncthreads();   // all sH(X) reads + dump reads done -> overwrite as d1
#pragma unroll
  for (int n = 0; n < 4; ++n) {
    const int col0 = (wn << 6) + n * 16 + (lhi << 2);
    const float4v bv = *(const float4v*)(bd1 + col0);
    const int c2 = col0 >> 3;
#pragma unroll
    for (int m = 0; m < 4; ++m) {
      const int row = rb + m * 16 + lrow;
      const int slot2 = (c2 & ~7) | ((c2 & 7) ^ (row & 7));
      u16x4 h;
#pragma unroll
      for (int q = 0; q < 4; ++q) h[q] = f2bf(fast_tanh(acc[m][n][q] + bv[q]));
      *(u16x4*)(sH + (row << 9) + (slot2 << 3) + (col0 & 7)) = h;
    }
  }
  __syncthreads();

  // ---- recon decoder layer 2: N=128, wave owns one 16-col frag (nf=wn) ----
  f32x4 acc2[4];
#pragma unroll
  for (int m = 0; m < 4; ++m) acc2[m] = (f32x4){0.f, 0.f, 0.f, 0.f};

  {
    const unsigned short* bl = Wd2t + (lane << 3);
    const int nfb = wn << 4;
    bf16x8 c0, c1;
    c0 = *(const bf16x8*)(bl + ((nfb + 0) << 9));
    for (int kk = 0; kk < 16; kk += 2) {
      c1 = *(const bf16x8*)(bl + ((nfb + kk + 1) << 9));
      {
        const int c = (kk << 2) + lhi;
        const int slot = (c & ~7) | ((c & 7) ^ sw);
#pragma unroll
        for (int m = 0; m < 4; ++m) {
          bf16x8 af = *(const bf16x8*)(sH + ((rb + m * 16 + lrow) << 9) + (slot << 3));
          acc2[m] = MFMA(c0, af, acc2[m]);
        }
      }
      if (kk + 2 < 16)
        c0 = *(const bf16x8*)(bl + ((nfb + kk + 2) << 9));
      {
        const int c = ((kk + 1) << 2) + lhi;
        const int slot = (c & ~7) | ((c & 7) ^ sw);
#pragma unroll
        for (int m = 0; m < 4; ++m) {
          bf16x8 af = *(const bf16x8*)(sH + ((rb + m * 16 + lrow) << 9) + (slot << 3));
          acc2[m] = MFMA(c1, af, acc2[m]);
        }
      }
    }
  }
  {
    const int col0 = (wn << 4) + (lhi << 2);
    const float4v bv = *(const float4v*)(bd2 + col0);
#pragma unroll
    for (int m = 0; m < 4; ++m) {
      const int row = rb + m * 16 + lrow;
      float4v o;
#pragma unroll
      for (int q = 0; q < 4; ++q) o[q] = fast_tanh(acc2[m][q] + bv[q]);
      *(float4v*)(outr + (size_t)(m0 + row) * IN_D + col0) = o;
    }
  }
}

// ---------------------------------------------------------------------------
// Fused 2-layer decoder (pred pass). 1024 thr = 16 waves, 128 rows/block.
// ---------------------------------------------------------------------------
__global__ __launch_bounds__(1024) void dec_fused_k(
    const unsigned short* __restrict__ X,
    const unsigned short* __restrict__ Wd1t,
    const unsigned short* __restrict__ Wd2t,
    const float* __restrict__ bd1, const float* __restrict__ bd2,
    float* __restrict__ out)
{
  __shared__ __attribute__((aligned(16))) unsigned short sH[128 * 512];  // 128 KB
  unsigned short* sX = sH;

  const int tid = threadIdx.x;
  const int m0 = blockIdx.x * 128;
  const int wave = tid >> 6, lane = tid & 63;
  const int wm = wave >> 3, wn = wave & 7;
  const int rb = wm << 6;
  const int lrow = lane & 15, lhi = lane >> 4, sw = lrow & 7;

  char* lX = (char*)sX + tid * 16;
#pragma unroll
  for (int p = 0; p < 8; ++p) {
    int id = (p << 10) + tid;
    int row = id >> 6, cc = id & 63;
    int gcc = (cc & ~7) | ((cc & 7) ^ (row & 7));
    gload_lds16(X + ((size_t)(m0 + row) << 9) + (gcc << 3), lX + (p << 14));
  }
  __syncthreads();

  f32x4 acc[4][4];
#pragma unroll
  for (int m = 0; m < 4; ++m)
#pragma unroll
    for (int n = 0; n < 4; ++n) acc[m][n] = (f32x4){0.f, 0.f, 0.f, 0.f};

  {
    const unsigned short* bl = Wd1t + (lane << 3);
    const int nfb = (wn << 2) << 4;
    bf16x8 b0[4], b1[4];
#pragma unroll
    for (int n = 0; n < 4; ++n)
      b0[n] = *(const bf16x8*)(bl + ((nfb + (n << 4)) << 9));
    for (int kk = 0; kk < 16; kk += 2) {
#pragma unroll
      for (int n = 0; n < 4; ++n)
        b1[n] = *(const bf16x8*)(bl + ((nfb + (n << 4) + kk + 1) << 9));
      {
        const int c = (kk << 2) + lhi;
        const int slot = (c & ~7) | ((c & 7) ^ sw);
        bf16x8 af[4];
#pragma unroll
        for (int m = 0; m < 4; ++m)
          af[m] = *(const bf16x8*)(sX + ((rb + m * 16 + lrow) << 9) + (slot << 3));
#pragma unroll
        for (int n = 0; n < 4; ++n)
#pragma unroll
          for (int m = 0; m < 4; ++m)
            acc[m][n] = MFMA(b0[n], af[m], acc[m][n]);
      }
      if (kk + 2 < 16) {
#pragma unroll
        for (int n = 0; n < 4; ++n)
          b0[n] = *(const bf16x8*)(bl + ((nfb + (n << 4) + kk + 2) << 9));
      }
      {
        const int c = ((kk + 1) << 2) + lhi;
        const int slot = (c & ~7) | ((c & 7) ^ sw);
        bf16x8 af[4];
#pragma unroll
        for (int m = 0; m < 4; ++m)
          af[m] = *(const bf16x8*)(sX + ((rb + m * 16 + lrow) << 9) + (slot << 3));
#pragma unroll
        for (int n = 0; n < 4; ++n)
#pragma unroll
          for (int m = 0; m < 4; ++m)
            acc[m][n] = MFMA(b1[n], af[m], acc[m][n]);
      }
    }
  }
  __syncthreads();
#pragma unroll
  for (int n = 0; n < 4; ++n) {
    const int col0 = (wn << 6) + n * 16 + (lhi << 2);
    const float4v bv = *(const float4v*)(bd1 + col0);
    const int c2 = col0 >> 3;
#pragma unroll
    for (int m = 0; m < 4; ++m) {
      const int row = rb + m * 16 + lrow;
      const int slot2 = (c2 & ~7) | ((c2 & 7) ^ (row & 7));
      u16x4 h;
#pragma unroll
      for (int q = 0; q < 4; ++q) h[q] = f2bf(fast_tanh(acc[m][n][q] + bv[q]));
      *(u16x4*)(sH + (row << 9) + (slot2 << 3) + (col0 & 7)) = h;
    }
  }
  __syncthreads();

  f32x4 acc2[4];
#pragma unroll
  for (int m = 0; m < 4; ++m) acc2[m] = (f32x4){0.f, 0.f, 0.f, 0.f};

  {
    const unsigned short* bl = Wd2t + (lane << 3);
    const int nfb = wn << 4;
    bf16x8 c0, c1;
    c0 = *(const bf16x8*)(bl + ((nfb + 0) << 9));
    for (int kk = 0; kk < 16; kk += 2) {
      c1 = *(const bf16x8*)(bl + ((nfb + kk + 1) << 9));
      {
        const int c = (kk << 2) + lhi;
        const int slot = (c & ~7) | ((c & 7) ^ sw);
#pragma unroll
        for (int m = 0; m < 4; ++m) {
          bf16x8 af = *(const bf16x8*)(sH + ((rb + m * 16 + lrow) << 9) + (slot << 3));
          acc2[m] = MFMA(c0, af, acc2[m]);
        }
      }
      if (kk + 2 < 16)
        c0 = *(const bf16x8*)(bl + ((nfb + kk + 2) << 9));
      {
        const int c = ((kk + 1) << 2) + lhi;
        const int slot = (c & ~7) | ((c & 7) ^ sw);
#pragma unroll
        for (int m = 0; m < 4; ++m) {
          bf16x8 af = *(const bf16x8*)(sH + ((rb + m * 16 + lrow) << 9) + (slot << 3));
          acc2[m] = MFMA(c1, af, acc2[m]);
        }
      }
    }
  }
  {
    const int col0 = (wn << 4) + (lhi << 2);
    const float4v bv = *(const float4v*)(bd2 + col0);
#pragma unroll
    for (int m = 0; m < 4; ++m) {
      const int row = rb + m * 16 + lrow;
      float4v o;
#pragma unroll
      for (int q = 0; q < 4; ++q) o[q] = fast_tanh(acc2[m][q] + bv[q]);
      *(float4v*)(out + (size_t)(m0 + row) * IN_D + col0) = o;
    }
  }
}

// ---------------------------------------------------------------------------
// rec_all: ALL 5 recurrence steps in one kernel. Block = one chain (32 rows).
// xsall traffic NON-TEMPORAL (bypass L2) so Wrec stays L2-resident; dump via
// sA (linear) in full-line coalesced u16x8 rows.
// ---------------------------------------------------------------------------
__global__ __launch_bounds__(512) void rec_all_k(
    const unsigned short* __restrict__ Wrec,
    unsigned short* __restrict__ xsall)   // in: xseq rows at t0; out: pred states
{
  __shared__ float xst[32][516];                                        // 64.5 KB
  __shared__ __attribute__((aligned(16))) unsigned short sA[32 * 512];  // 32 KB

  const int tid = threadIdx.x;
  const int chain = blockIdx.x;
  const int t0 = chain * 5;
  const int wave = tid >> 6, lane = tid & 63;
  const int wn = wave;
  const int lrow = lane & 15, lhi = lane >> 4, sw = lrow & 7;

  // coalesced init: xsall[row, t0, :] bf16 -> xst f32 (non-temporal read)
#pragma unroll
  for (int p = 0; p < 4; ++p) {
    int id = (p << 9) + tid;
    int row = id >> 6, c8 = (id & 63) << 3;
    u16x8 v = __builtin_nontemporal_load(
        (const u16x8*)(xsall + (((size_t)row * T_SZ + t0) << 9) + c8));
#pragma unroll
    for (int e = 0; e < 8; ++e) xst[row][c8 + e] = bf2f(v[e]);
  }
  __syncthreads();

  const unsigned short* bl = Wrec + (lane << 3);
  const int nfb = (wn << 2) << 4;

  for (int s = 0; s < 5; ++s) {
    // stage tanh(xst) -> sA (swizzled)
#pragma unroll
    for (int p = 0; p < 4; ++p) {
      int id = (p << 9) + tid;
      int row = id >> 6, cc = id & 63;
      int gc = (cc & ~7) | ((cc & 7) ^ (row & 7));
      const float* src = &xst[row][gc << 3];
      float4v u0 = *(const float4v*)src;
      float4v u1 = *(const float4v*)(src + 4);
      u16x8 h;
      h[0] = f2bf(fast_tanh(u0[0])); h[1] = f2bf(fast_tanh(u0[1]));
      h[2] = f2bf(fast_tanh(u0[2])); h[3] = f2bf(fast_tanh(u0[3]));
      h[4] = f2bf(fast_tanh(u1[0])); h[5] = f2bf(fast_tanh(u1[1]));
      h[6] = f2bf(fast_tanh(u1[2])); h[7] = f2bf(fast_tanh(u1[3]));
      *(u16x8*)(sA + (row << 9) + (cc << 3)) = h;
    }
    __syncthreads();

    f32x4 acc[2][4];
#pragma unroll
    for (int m = 0; m < 2; ++m)
#pragma unroll
      for (int n = 0; n < 4; ++n) acc[m][n] = (f32x4){0.f, 0.f, 0.f, 0.f};

    bf16x8 b0[4], b1[4];
#pragma unroll
    for (int n = 0; n < 4; ++n)
      b0[n] = *(const bf16x8*)(bl + ((nfb + (n << 4)) << 9));
    for (int kk = 0; kk < 16; kk += 2) {
#pragma unroll
      for (int n = 0; n < 4; ++n)
        b1[n] = *(const bf16x8*)(bl + ((nfb + (n << 4) + kk + 1) << 9));
      {
        const int c = (kk << 2) + lhi;
        const int slot = (c & ~7) | ((c & 7) ^ sw);
        bf16x8 af0 = *(const bf16x8*)(sA + (lrow << 9) + (slot << 3));
        bf16x8 af1 = *(const bf16x8*)(sA + ((16 + lrow) << 9) + (slot << 3));
#pragma unroll
        for (int n = 0; n < 4; ++n) {
          acc[0][n] = MFMA(b0[n], af0, acc[0][n]);
          acc[1][n] = MFMA(b0[n], af1, acc[1][n]);
        }
      }
      if (kk + 2 < 16) {
#pragma unroll
        for (int n = 0; n < 4; ++n)
          b0[n] = *(const bf16x8*)(bl + ((nfb + (n << 4) + kk + 2) << 9));
      }
      {
        const int c = ((kk + 1) << 2) + lhi;
        const int slot = (c & ~7) | ((c & 7) ^ sw);
        bf16x8 af0 = *(const bf16x8*)(sA + (lrow << 9) + (slot << 3));
        bf16x8 af1 = *(const bf16x8*)(sA + ((16 + lrow) << 9) + (slot << 3));
#pragma unroll
        for (int n = 0; n < 4; ++n) {
          acc[0][n] = MFMA(b1[n], af0, acc[0][n]);
          acc[1][n] = MFMA(b1[n], af1, acc[1][n]);
        }
      }
    }
    __syncthreads();   // all k-loop reads of sA complete -> safe to overwrite

    // epilogue: update xst in place + write xnew bf16 into sA (LINEAR)
#pragma unroll
    for (int n = 0; n < 4; ++n) {
      const int col0 = (wn << 6) + n * 16 + (lhi << 2);
#pragma unroll
      for (int m = 0; m < 2; ++m) {
        const int row = m * 16 + lrow;
        float4v x = *(const float4v*)(&xst[row][col0]);
        float4v xn;
        u16x4 h;
#pragma unroll
        for (int q = 0; q < 4; ++q) {
          xn[q] = x[q] + (acc[m][n][q] - x[q]) * INV_TAUX;
          h[q] = f2bf(xn[q]);
        }
        *(float4v*)(&xst[row][col0]) = xn;
        *(u16x4*)(sA + (row << 9) + col0) = h;
      }
    }
    __syncthreads();   // sA fully written by all waves

    // non-temporal coalesced dump: sA -> xsall[:, t, :] (bypass L2)
    const int t = t0 + s;
    if (t < T_SZ) {
#pragma unroll
      for (int p = 0; p < 4; ++p) {
        int id = (p << 9) + tid;
        int row = id >> 6, c8 = (id & 63) << 3;
        u16x8 v = *(const u16x8*)(sA + (row << 9) + c8);
        __builtin_nontemporal_store(
            v, (u16x8*)(xsall + (((size_t)row * T_SZ + t) << 9) + c8));
      }
    }
    __syncthreads();   // dump reads done before next step's staging overwrites
  }
}

// weight prep into fragment-linear layout:
// flat[((nf*nk+kk)*64+lane)*8+e] = B[nf*16+(lane&15)][kk*32+(lane>>4)*8+e]
__global__ void prep_k(const float* __restrict__ We1, const float* __restrict__ We2,
                       const float* __restrict__ We3, const float* __restrict__ Wd1,
                       const float* __restrict__ Wd2, const float* __restrict__ W,
                       unsigned short* __restrict__ wt) {
  int idx = blockIdx.x * blockDim.x + threadIdx.x;
  if (idx >= 1179648) return;
  unsigned short v;
  if (idx < 65536) {
    int i = idx, lane = (i >> 3) & 63, t2 = i >> 9;
    int kk = t2 & 3, nf = t2 >> 2;
    int n = (nf << 4) + (lane & 15), k = (kk << 5) + ((lane >> 4) << 3) + (i & 7);
    v = f2bf(We1[k * 512 + n]);
  } else if (idx < 327680) {
    int i = idx - 65536, lane = (i >> 3) & 63, t2 = i >> 9;
    int kk = t2 & 15, nf = t2 >> 4;
    int n = (nf << 4) + (lane & 15), k = (kk << 5) + ((lane >> 4) << 3) + (i & 7);
    v = f2bf(We2[k * 512 + n]);
  } else if (idx < 589824) {
    int i = idx - 327680, lane = (i >> 3) & 63, t2 = i >> 9;
    int kk = t2 & 15, nf = t2 >> 4;
    int n = (nf << 4) + (lane & 15), k = (kk << 5) + ((lane >> 4) << 3) + (i & 7);
    v = f2bf(We3[k * 512 + n]);
  } else if (idx < 851968) {
    int i = idx - 589824, lane = (i >> 3) & 63, t2 = i >> 9;
    int kk = t2 & 15, nf = t2 >> 4;
    int n = (nf << 4) + (lane & 15), k = (kk << 5) + ((lane >> 4) << 3) + (i & 7);
    v = f2bf(Wd1[k * 512 + n]);
  } else if (idx < 917504) {
    int i = idx - 851968, lane = (i >> 3) & 63, t2 = i >> 9;
    int kk = t2 & 15, nf = t2 >> 4;
    int n = (nf << 4) + (lane & 15), k = (kk << 5) + ((lane >> 4) << 3) + (i & 7);
    v = f2bf(Wd2[k * 128 + n]);
  } else {
    int i = idx - 917504, lane = (i >> 3) & 63, t2 = i >> 9;
    int kk = t2 & 15, nf = t2 >> 4;
    int n = (nf << 4) + (lane & 15), k = (kk << 5) + ((lane >> 4) << 3) + (i & 7);
    v = f2bf(W[(n << 9) + k]);
  }
  wt[idx] = v;
}

__global__ void sentinel_k(float* out, float v) { out[0] = v; }

extern "C" void kernel_launch(void* const* d_in, const int* in_sizes, int n_in,
                              void* d_out, int out_size, void* d_ws, size_t ws_size,
                              hipStream_t stream) {
  const float* in_seq = (const float*)d_in[0];
  const float* We1 = (const float*)d_in[1];
  const float* be1 = (const float*)d_in[2];
  const float* We2 = (const float*)d_in[3];
  const float* be2 = (const float*)d_in[4];
  const float* We3 = (const float*)d_in[5];
  const float* be3 = (const float*)d_in[6];
  const float* Wd1 = (const float*)d_in[7];
  const float* bd1 = (const float*)d_in[8];
  const float* Wd2 = (const float*)d_in[9];
  const float* bd2 = (const float*)d_in[10];
  const float* W   = (const float*)d_in[11];

  const int NROW = B_SZ * T_SZ;                       // 65536
  const size_t OFF_XSEQ = 0;                          // 67,108,864 B
  const size_t OFF_WT   = (size_t)NROW * HID * 2;     // 67,108,864
  const size_t REQUIRED = OFF_WT + 2359296;           // 69,468,160

  float* outp = (float*)d_out;
  float* outr = outp + (size_t)NROW * IN_D;

  if (ws_size < REQUIRED) {
    sentinel_k<<<1, 1, 0, stream>>>(outp, (float)(ws_size >> 20));
    return;
  }

  char* ws = (char*)d_ws;
  unsigned short* xseq = (unsigned short*)(ws + OFF_XSEQ);  // reused as xsall
  unsigned short* wt   = (unsigned short*)(ws + OFF_WT);
  unsigned short* Wd1t = wt + 589824;
  unsigned short* Wd2t = wt + 851968;
  unsigned short* Wrec = wt + 917504;

  prep_k<<<4608, 256, 0, stream>>>(We1, We2, We3, Wd1, Wd2, W, wt);
  enc5_k<<<512, 1024, 0, stream>>>(in_seq, wt, be1, be2, be3,
                                   Wd1t, Wd2t, bd1, bd2, xseq, outr);
  rec_all_k<<<NCHAIN, 512, 0, stream>>>(Wrec, xseq);
  dec_fused_k<<<512, 1024, 0, stream>>>(xseq, Wd1t, Wd2t, bd1, bd2, outp);
}

// Round 22
// 416.172 us; speedup vs baseline: 1.1357x; 1.0437x over previous
//
#include <hip/hip_runtime.h>
#include <stdint.h>

#define B_SZ  32
#define T_SZ  2048
#define IN_D  128
#define HID   512
#define NCHAIN 410              // ceil(T/5)
#define INV_TAUX 0.005f         // 1/200

typedef __attribute__((ext_vector_type(8))) short bf16x8;
typedef __attribute__((ext_vector_type(4))) float f32x4;
typedef __attribute__((ext_vector_type(4))) float float4v;
typedef __attribute__((ext_vector_type(4))) unsigned short u16x4;
typedef __attribute__((ext_vector_type(8))) unsigned short u16x8;

// Operands SWAPPED: mfma(b, a) => D^T. Lane holds row = frag_m*16 + (lane&15),
// cols = frag_n*16 + (lane>>4)*4 + q (4 consecutive) -> vectorized epilogues.
#define MFMA(b, a, c) __builtin_amdgcn_mfma_f32_16x16x32_bf16((b), (a), (c), 0, 0, 0)

__device__ __forceinline__ unsigned short f2bf(float x) {
  union { float f; unsigned int u; } v; v.f = x;
  unsigned int r = v.u + 0x7FFFu + ((v.u >> 16) & 1u);  // RNE
  return (unsigned short)(r >> 16);
}
__device__ __forceinline__ float bf2f(unsigned short b) {
  union { unsigned int u; float f; } v; v.u = ((unsigned int)b) << 16;
  return v.f;
}
__device__ __forceinline__ float fast_tanh(float x) {
  float ax = fabsf(x);
  float e = __expf(-2.0f * ax);
  float r = (1.0f - e) * __builtin_amdgcn_rcpf(1.0f + e);
  return x < 0.0f ? -r : r;
}
__device__ __forceinline__ void gload_lds16(const void* g, void* l) {
  __builtin_amdgcn_global_load_lds(
      reinterpret_cast<__attribute__((address_space(1))) void*>(reinterpret_cast<uintptr_t>(g)),
      reinterpret_cast<__attribute__((address_space(3))) void*>(reinterpret_cast<uintptr_t>(l)),
      16, 0, 0);
}

// ---------------------------------------------------------------------------
// FINAL (round-16 measured best, 415.8us): enc5/dec = 1024-thread blocks
// (16 waves = 2wm x 8wn, 128 rows/block, MF=4 per wave); rec_all = persistent
// per-chain kernel with LDS f32 state. Weights FRAGMENT-LINEAR (see prep_k).
// ---------------------------------------------------------------------------

// ---------------------------------------------------------------------------
// enc5: 3 encoder layers + xseq dump + 2 recon-decoder layers, one kernel.
// 1024 thr = 16 waves (2 wm x 8 wn), 128 rows/block, LDS 128 KB.
// ---------------------------------------------------------------------------
__global__ __launch_bounds__(1024) void enc5_k(
    const float* __restrict__ in_seq,
    const unsigned short* __restrict__ wt,
    const float* __restrict__ be1, const float* __restrict__ be2,
    const float* __restrict__ be3,
    const unsigned short* __restrict__ Wd1t,
    const unsigned short* __restrict__ Wd2t,
    const float* __restrict__ bd1, const float* __restrict__ bd2,
    unsigned short* __restrict__ xseq,
    float* __restrict__ outr)
{
  __shared__ __attribute__((aligned(16))) unsigned short sH[128 * 512];  // 128 KB
  unsigned short* sA = sH;   // alias: input tile (128x128) in sH's head

  const int tid = threadIdx.x;
  const int m0 = blockIdx.x * 128;
  const int wave = tid >> 6, lane = tid & 63;
  const int wm = wave >> 3, wn = wave & 7;
  const int rb = wm << 6;                    // wave's row base (0 or 64)
  const int lrow = lane & 15, lhi = lane >> 4, sw = lrow & 7;

  // stage input tile f32 -> bf16, chunk-swizzled (128 rows x 16 chunks)
#pragma unroll
  for (int p = 0; p < 2; ++p) {
    int id = (p << 10) + tid;
    int row = id >> 4, cc = id & 15;
    const float* src = in_seq + (size_t)(m0 + row) * IN_D + (cc << 3);
    float4v u0 = *(const float4v*)src;
    float4v u1 = *(const float4v*)(src + 4);
    u16x8 h;
    h[0] = f2bf(u0[0]); h[1] = f2bf(u0[1]); h[2] = f2bf(u0[2]); h[3] = f2bf(u0[3]);
    h[4] = f2bf(u1[0]); h[5] = f2bf(u1[1]); h[6] = f2bf(u1[2]); h[7] = f2bf(u1[3]);
    int slot = (cc & 8) | ((cc & 7) ^ (row & 7));
    *(u16x8*)(sA + (row << 7) + (slot << 3)) = h;
  }
  __syncthreads();

  f32x4 acc[4][4];
  const unsigned short* Bts[3] = {wt, wt + 65536, wt + 327680};
  const float* bss[3] = {be1, be2, be3};

  // ---- 3 encoder layers (in-place in sH) ----
  for (int l = 0; l < 3; ++l) {
    const int lstr = (l == 0) ? 128 : 512;
    const int nk = (l == 0) ? 4 : 16;
    const unsigned short* bl = Bts[l] + (lane << 3);
    const int nfb = (wn << 2) * nk;
    const float* bias = bss[l];

#pragma unroll
    for (int m = 0; m < 4; ++m)
#pragma unroll
      for (int n = 0; n < 4; ++n) acc[m][n] = (f32x4){0.f, 0.f, 0.f, 0.f};

    bf16x8 b0[4], b1[4];
#pragma unroll
    for (int n = 0; n < 4; ++n)
      b0[n] = *(const bf16x8*)(bl + ((nfb + n * nk) << 9));

    for (int kk = 0; kk < nk; kk += 2) {
#pragma unroll
      for (int n = 0; n < 4; ++n)
        b1[n] = *(const bf16x8*)(bl + ((nfb + n * nk + kk + 1) << 9));
      {
        const int c = (kk << 2) + lhi;
        const int slot = (c & ~7) | ((c & 7) ^ sw);
        bf16x8 af[4];
#pragma unroll
        for (int m = 0; m < 4; ++m)
          af[m] = *(const bf16x8*)(sH + (rb + m * 16 + lrow) * lstr + (slot << 3));
#pragma unroll
        for (int n = 0; n < 4; ++n)
#pragma unroll
          for (int m = 0; m < 4; ++m)
            acc[m][n] = MFMA(b0[n], af[m], acc[m][n]);
      }
      if (kk + 2 < nk) {
#pragma unroll
        for (int n = 0; n < 4; ++n)
          b0[n] = *(const bf16x8*)(bl + ((nfb + n * nk + kk + 2) << 9));
      }
      {
        const int c = ((kk + 1) << 2) + lhi;
        const int slot = (c & ~7) | ((c & 7) ^ sw);
        bf16x8 af[4];
#pragma unroll
        for (int m = 0; m < 4; ++m)
          af[m] = *(const bf16x8*)(sH + (rb + m * 16 + lrow) * lstr + (slot << 3));
#pragma unroll
        for (int n = 0; n < 4; ++n)
#pragma unroll
          for (int m = 0; m < 4; ++m)
            acc[m][n] = MFMA(b1[n], af[m], acc[m][n]);
      }
    }
    __syncthreads();
    // epilogue: acc[m][n][q] = D[row=rb+m*16+lrow][col=wn*64+n*16+lhi*4+q]
#pragma unroll
    for (int n = 0; n < 4; ++n) {
      const int col0 = (wn << 6) + n * 16 + (lhi << 2);
      const float4v bv = *(const float4v*)(bias + col0);
      const int c2 = col0 >> 3;
#pragma unroll
      for (int m = 0; m < 4; ++m) {
        const int row = rb + m * 16 + lrow;
        const int slot2 = (c2 & ~7) | ((c2 & 7) ^ (row & 7));
        u16x4 h;
#pragma unroll
        for (int q = 0; q < 4; ++q) h[q] = f2bf(fast_tanh(acc[m][n][q] + bv[q]));
        *(u16x4*)(sH + (row << 9) + (slot2 << 3) + (col0 & 7)) = h;
      }
    }
    __syncthreads();
  }

  // ---- dump xseq (coalesced un-swizzle; read-only on sH) ----
#pragma unroll
  for (int p = 0; p < 8; ++p) {
    int id = (p << 10) + tid;
    int row = id >> 6, cc = id & 63;
    int slot = (cc & ~7) | ((cc & 7) ^ (row & 7));
    u16x8 v = *(const u16x8*)(sH + (row << 9) + (slot << 3));
    *(u16x8*)(xseq + ((size_t)(m0 + row) << 9) + (cc << 3)) = v;
  }

  // ---- recon decoder layer 1 (reads sH-as-X, writes sH-as-d1 in place) ----
#pragma unroll
  for (int m = 0; m < 4; ++m)
#pragma unroll
    for (int n = 0; n < 4; ++n) acc[m][n] = (f32x4){0.f, 0.f, 0.f, 0.f};

  {
    const unsigned short* bl = Wd1t + (lane << 3);
    const int nfb = (wn << 2) << 4;
    bf16x8 b0[4], b1[4];
#pragma unroll
    for (int n = 0; n < 4; ++n)
      b0[n] = *(const bf16x8*)(bl + ((nfb + (n << 4)) << 9));
    for (int kk = 0; kk < 16; kk += 2) {
#pragma unroll
      for (int n = 0; n < 4; ++n)
        b1[n] = *(const bf16x8*)(bl + ((nfb + (n << 4) + kk + 1) << 9));
      {
        const int c = (kk << 2) + lhi;
        const int slot = (c & ~7) | ((c & 7) ^ sw);
        bf16x8 af[4];
#pragma unroll
        for (int m = 0; m < 4; ++m)
          af[m] = *(const bf16x8*)(sH + ((rb + m * 16 + lrow) << 9) + (slot << 3));
#pragma unroll
        for (int n = 0; n < 4; ++n)
#pragma unroll
          for (int m = 0; m < 4; ++m)
            acc[m][n] = MFMA(b0[n], af[m], acc[m][n]);
      }
      if (kk + 2 < 16) {
#pragma unroll
        for (int n = 0; n < 4; ++n)
          b0[n] = *(const bf16x8*)(bl + ((nfb + (n << 4) + kk + 2) << 9));
      }
      {
        const int c = ((kk + 1) << 2) + lhi;
        const int slot = (c & ~7) | ((c & 7) ^ sw);
        bf16x8 af[4];
#pragma unroll
        for (int m = 0; m < 4; ++m)
          af[m] = *(const bf16x8*)(sH + ((rb + m * 16 + lrow) << 9) + (slot << 3));
#pragma unroll
        for (int n = 0; n < 4; ++n)
#pragma unroll
          for (int m = 0; m < 4; ++m)
            acc[m][n] = MFMA(b1[n], af[m], acc[m][n]);
      }
    }
  }
  __syncthreads();   // all sH(X) reads + dump reads done -> overwrite as d1
#pragma unroll
  for (int n = 0; n < 4; ++n) {
    const int col0 = (wn << 6) + n * 16 + (lhi << 2);
    const float4v bv = *(const float4v*)(bd1 + col0);
    const int c2 = col0 >> 3;
#pragma unroll
    for (int m = 0; m < 4; ++m) {
      const int row = rb + m * 16 + lrow;
      const int slot2 = (c2 & ~7) | ((c2 & 7) ^ (row & 7));
      u16x4 h;
#pragma unroll
      for (int q = 0; q < 4; ++q) h[q] = f2bf(fast_tanh(acc[m][n][q] + bv[q]));
      *(u16x4*)(sH + (row << 9) + (slot2 << 3) + (col0 & 7)) = h;
    }
  }
  __syncthreads();

  // ---- recon decoder layer 2: N=128, wave owns one 16-col frag (nf=wn) ----
  f32x4 acc2[4];
#pragma unroll
  for (int m = 0; m < 4; ++m) acc2[m] = (f32x4){0.f, 0.f, 0.f, 0.f};

  {
    const unsigned short* bl = Wd2t + (lane << 3);
    const int nfb = wn << 4;
    bf16x8 c0, c1;
    c0 = *(const bf16x8*)(bl + ((nfb + 0) << 9));
    for (int kk = 0; kk < 16; kk += 2) {
      c1 = *(const bf16x8*)(bl + ((nfb + kk + 1) << 9));
      {
        const int c = (kk << 2) + lhi;
        const int slot = (c & ~7) | ((c & 7) ^ sw);
#pragma unroll
        for (int m = 0; m < 4; ++m) {
          bf16x8 af = *(const bf16x8*)(sH + ((rb + m * 16 + lrow) << 9) + (slot << 3));
          acc2[m] = MFMA(c0, af, acc2[m]);
        }
      }
      if (kk + 2 < 16)
        c0 = *(const bf16x8*)(bl + ((nfb + kk + 2) << 9));
      {
        const int c = ((kk + 1) << 2) + lhi;
        const int slot = (c & ~7) | ((c & 7) ^ sw);
#pragma unroll
        for (int m = 0; m < 4; ++m) {
          bf16x8 af = *(const bf16x8*)(sH + ((rb + m * 16 + lrow) << 9) + (slot << 3));
          acc2[m] = MFMA(c1, af, acc2[m]);
        }
      }
    }
  }
  {
    const int col0 = (wn << 4) + (lhi << 2);
    const float4v bv = *(const float4v*)(bd2 + col0);
#pragma unroll
    for (int m = 0; m < 4; ++m) {
      const int row = rb + m * 16 + lrow;
      float4v o;
#pragma unroll
      for (int q = 0; q < 4; ++q) o[q] = fast_tanh(acc2[m][q] + bv[q]);
      *(float4v*)(outr + (size_t)(m0 + row) * IN_D + col0) = o;
    }
  }
}

// ---------------------------------------------------------------------------
// Fused 2-layer decoder (pred pass). 1024 thr = 16 waves, 128 rows/block.
// ---------------------------------------------------------------------------
__global__ __launch_bounds__(1024) void dec_fused_k(
    const unsigned short* __restrict__ X,
    const unsigned short* __restrict__ Wd1t,
    const unsigned short* __restrict__ Wd2t,
    const float* __restrict__ bd1, const float* __restrict__ bd2,
    float* __restrict__ out)
{
  __shared__ __attribute__((aligned(16))) unsigned short sH[128 * 512];  // 128 KB
  unsigned short* sX = sH;

  const int tid = threadIdx.x;
  const int m0 = blockIdx.x * 128;
  const int wave = tid >> 6, lane = tid & 63;
  const int wm = wave >> 3, wn = wave & 7;
  const int rb = wm << 6;
  const int lrow = lane & 15, lhi = lane >> 4, sw = lrow & 7;

  char* lX = (char*)sX + tid * 16;
#pragma unroll
  for (int p = 0; p < 8; ++p) {
    int id = (p << 10) + tid;
    int row = id >> 6, cc = id & 63;
    int gcc = (cc & ~7) | ((cc & 7) ^ (row & 7));
    gload_lds16(X + ((size_t)(m0 + row) << 9) + (gcc << 3), lX + (p << 14));
  }
  __syncthreads();

  f32x4 acc[4][4];
#pragma unroll
  for (int m = 0; m < 4; ++m)
#pragma unroll
    for (int n = 0; n < 4; ++n) acc[m][n] = (f32x4){0.f, 0.f, 0.f, 0.f};

  {
    const unsigned short* bl = Wd1t + (lane << 3);
    const int nfb = (wn << 2) << 4;
    bf16x8 b0[4], b1[4];
#pragma unroll
    for (int n = 0; n < 4; ++n)
      b0[n] = *(const bf16x8*)(bl + ((nfb + (n << 4)) << 9));
    for (int kk = 0; kk < 16; kk += 2) {
#pragma unroll
      for (int n = 0; n < 4; ++n)
        b1[n] = *(const bf16x8*)(bl + ((nfb + (n << 4) + kk + 1) << 9));
      {
        const int c = (kk << 2) + lhi;
        const int slot = (c & ~7) | ((c & 7) ^ sw);
        bf16x8 af[4];
#pragma unroll
        for (int m = 0; m < 4; ++m)
          af[m] = *(const bf16x8*)(sX + ((rb + m * 16 + lrow) << 9) + (slot << 3));
#pragma unroll
        for (int n = 0; n < 4; ++n)
#pragma unroll
          for (int m = 0; m < 4; ++m)
            acc[m][n] = MFMA(b0[n], af[m], acc[m][n]);
      }
      if (kk + 2 < 16) {
#pragma unroll
        for (int n = 0; n < 4; ++n)
          b0[n] = *(const bf16x8*)(bl + ((nfb + (n << 4) + kk + 2) << 9));
      }
      {
        const int c = ((kk + 1) << 2) + lhi;
        const int slot = (c & ~7) | ((c & 7) ^ sw);
        bf16x8 af[4];
#pragma unroll
        for (int m = 0; m < 4; ++m)
          af[m] = *(const bf16x8*)(sX + ((rb + m * 16 + lrow) << 9) + (slot << 3));
#pragma unroll
        for (int n = 0; n < 4; ++n)
#pragma unroll
          for (int m = 0; m < 4; ++m)
            acc[m][n] = MFMA(b1[n], af[m], acc[m][n]);
      }
    }
  }
  __syncthreads();
#pragma unroll
  for (int n = 0; n < 4; ++n) {
    const int col0 = (wn << 6) + n * 16 + (lhi << 2);
    const float4v bv = *(const float4v*)(bd1 + col0);
    const int c2 = col0 >> 3;
#pragma unroll
    for (int m = 0; m < 4; ++m) {
      const int row = rb + m * 16 + lrow;
      const int slot2 = (c2 & ~7) | ((c2 & 7) ^ (row & 7));
      u16x4 h;
#pragma unroll
      for (int q = 0; q < 4; ++q) h[q] = f2bf(fast_tanh(acc[m][n][q] + bv[q]));
      *(u16x4*)(sH + (row << 9) + (slot2 << 3) + (col0 & 7)) = h;
    }
  }
  __syncthreads();

  f32x4 acc2[4];
#pragma unroll
  for (int m = 0; m < 4; ++m) acc2[m] = (f32x4){0.f, 0.f, 0.f, 0.f};

  {
    const unsigned short* bl = Wd2t + (lane << 3);
    const int nfb = wn << 4;
    bf16x8 c0, c1;
    c0 = *(const bf16x8*)(bl + ((nfb + 0) << 9));
    for (int kk = 0; kk < 16; kk += 2) {
      c1 = *(const bf16x8*)(bl + ((nfb + kk + 1) << 9));
      {
        const int c = (kk << 2) + lhi;
        const int slot = (c & ~7) | ((c & 7) ^ sw);
#pragma unroll
        for (int m = 0; m < 4; ++m) {
          bf16x8 af = *(const bf16x8*)(sH + ((rb + m * 16 + lrow) << 9) + (slot << 3));
          acc2[m] = MFMA(c0, af, acc2[m]);
        }
      }
      if (kk + 2 < 16)
        c0 = *(const bf16x8*)(bl + ((nfb + kk + 2) << 9));
      {
        const int c = ((kk + 1) << 2) + lhi;
        const int slot = (c & ~7) | ((c & 7) ^ sw);
#pragma unroll
        for (int m = 0; m < 4; ++m) {
          bf16x8 af = *(const bf16x8*)(sH + ((rb + m * 16 + lrow) << 9) + (slot << 3));
          acc2[m] = MFMA(c1, af, acc2[m]);
        }
      }
    }
  }
  {
    const int col0 = (wn << 4) + (lhi << 2);
    const float4v bv = *(const float4v*)(bd2 + col0);
#pragma unroll
    for (int m = 0; m < 4; ++m) {
      const int row = rb + m * 16 + lrow;
      float4v o;
#pragma unroll
      for (int q = 0; q < 4; ++q) o[q] = fast_tanh(acc2[m][q] + bv[q]);
      *(float4v*)(out + (size_t)(m0 + row) * IN_D + col0) = o;
    }
  }
}

// ---------------------------------------------------------------------------
// rec_all: ALL 5 recurrence steps in one kernel. Block = one chain (32 rows).
// ---------------------------------------------------------------------------
__global__ __launch_bounds__(512) void rec_all_k(
    const unsigned short* __restrict__ Wrec,
    unsigned short* __restrict__ xsall)   // in: xseq rows at t0; out: pred states
{
  __shared__ float xst[32][516];                                        // 64.5 KB
  __shared__ __attribute__((aligned(16))) unsigned short sA[32 * 512];  // 32 KB

  const int tid = threadIdx.x;
  const int chain = blockIdx.x;
  const int t0 = chain * 5;
  const int wave = tid >> 6, lane = tid & 63;
  const int wn = wave;
  const int lrow = lane & 15, lhi = lane >> 4, sw = lrow & 7;

  // coalesced init: xsall[row, t0, :] bf16 -> xst f32
#pragma unroll
  for (int p = 0; p < 4; ++p) {
    int id = (p << 9) + tid;
    int row = id >> 6, c8 = (id & 63) << 3;
    u16x8 v = *(const u16x8*)(xsall + (((size_t)row * T_SZ + t0) << 9) + c8);
#pragma unroll
    for (int e = 0; e < 8; ++e) xst[row][c8 + e] = bf2f(v[e]);
  }
  __syncthreads();

  const unsigned short* bl = Wrec + (lane << 3);
  const int nfb = (wn << 2) << 4;

  for (int s = 0; s < 5; ++s) {
    // stage tanh(xst) -> sA (swizzled)
#pragma unroll
    for (int p = 0; p < 4; ++p) {
      int id = (p << 9) + tid;
      int row = id >> 6, cc = id & 63;
      int gc = (cc & ~7) | ((cc & 7) ^ (row & 7));
      const float* src = &xst[row][gc << 3];
      float4v u0 = *(const float4v*)src;
      float4v u1 = *(const float4v*)(src + 4);
      u16x8 h;
      h[0] = f2bf(fast_tanh(u0[0])); h[1] = f2bf(fast_tanh(u0[1]));
      h[2] = f2bf(fast_tanh(u0[2])); h[3] = f2bf(fast_tanh(u0[3]));
      h[4] = f2bf(fast_tanh(u1[0])); h[5] = f2bf(fast_tanh(u1[1]));
      h[6] = f2bf(fast_tanh(u1[2])); h[7] = f2bf(fast_tanh(u1[3]));
      *(u16x8*)(sA + (row << 9) + (cc << 3)) = h;
    }
    __syncthreads();

    f32x4 acc[2][4];
#pragma unroll
    for (int m = 0; m < 2; ++m)
#pragma unroll
      for (int n = 0; n < 4; ++n) acc[m][n] = (f32x4){0.f, 0.f, 0.f, 0.f};

    bf16x8 b0[4], b1[4];
#pragma unroll
    for (int n = 0; n < 4; ++n)
      b0[n] = *(const bf16x8*)(bl + ((nfb + (n << 4)) << 9));
    for (int kk = 0; kk < 16; kk += 2) {
#pragma unroll
      for (int n = 0; n < 4; ++n)
        b1[n] = *(const bf16x8*)(bl + ((nfb + (n << 4) + kk + 1) << 9));
      {
        const int c = (kk << 2) + lhi;
        const int slot = (c & ~7) | ((c & 7) ^ sw);
        bf16x8 af0 = *(const bf16x8*)(sA + (lrow << 9) + (slot << 3));
        bf16x8 af1 = *(const bf16x8*)(sA + ((16 + lrow) << 9) + (slot << 3));
#pragma unroll
        for (int n = 0; n < 4; ++n) {
          acc[0][n] = MFMA(b0[n], af0, acc[0][n]);
          acc[1][n] = MFMA(b0[n], af1, acc[1][n]);
        }
      }
      if (kk + 2 < 16) {
#pragma unroll
        for (int n = 0; n < 4; ++n)
          b0[n] = *(const bf16x8*)(bl + ((nfb + (n << 4) + kk + 2) << 9));
      }
      {
        const int c = ((kk + 1) << 2) + lhi;
        const int slot = (c & ~7) | ((c & 7) ^ sw);
        bf16x8 af0 = *(const bf16x8*)(sA + (lrow << 9) + (slot << 3));
        bf16x8 af1 = *(const bf16x8*)(sA + ((16 + lrow) << 9) + (slot << 3));
#pragma unroll
        for (int n = 0; n < 4; ++n) {
          acc[0][n] = MFMA(b1[n], af0, acc[0][n]);
          acc[1][n] = MFMA(b1[n], af1, acc[1][n]);
        }
      }
    }
    __syncthreads();   // all staging/k-loop reads of xst & sA complete

    // epilogue: update xst in place + write pred state at t = t0 + s
    const int t = t0 + s;
#pragma unroll
    for (int n = 0; n < 4; ++n) {
      const int col0 = (wn << 6) + n * 16 + (lhi << 2);
#pragma unroll
      for (int m = 0; m < 2; ++m) {
        const int row = m * 16 + lrow;
        float4v x = *(const float4v*)(&xst[row][col0]);
        float4v xn;
#pragma unroll
        for (int q = 0; q < 4; ++q) xn[q] = x[q] + (acc[m][n][q] - x[q]) * INV_TAUX;
        *(float4v*)(&xst[row][col0]) = xn;
        if (t < T_SZ) {
          u16x4 h;
#pragma unroll
          for (int q = 0; q < 4; ++q) h[q] = f2bf(xn[q]);
          *(u16x4*)(xsall + (((size_t)row * T_SZ + t) << 9) + col0) = h;
        }
      }
    }
    __syncthreads();   // xst updates visible before next step's staging
  }
}

// weight prep into fragment-linear layout:
// flat[((nf*nk+kk)*64+lane)*8+e] = B[nf*16+(lane&15)][kk*32+(lane>>4)*8+e]
__global__ void prep_k(const float* __restrict__ We1, const float* __restrict__ We2,
                       const float* __restrict__ We3, const float* __restrict__ Wd1,
                       const float* __restrict__ Wd2, const float* __restrict__ W,
                       unsigned short* __restrict__ wt) {
  int idx = blockIdx.x * blockDim.x + threadIdx.x;
  if (idx >= 1179648) return;
  unsigned short v;
  if (idx < 65536) {
    int i = idx, lane = (i >> 3) & 63, t2 = i >> 9;
    int kk = t2 & 3, nf = t2 >> 2;
    int n = (nf << 4) + (lane & 15), k = (kk << 5) + ((lane >> 4) << 3) + (i & 7);
    v = f2bf(We1[k * 512 + n]);
  } else if (idx < 327680) {
    int i = idx - 65536, lane = (i >> 3) & 63, t2 = i >> 9;
    int kk = t2 & 15, nf = t2 >> 4;
    int n = (nf << 4) + (lane & 15), k = (kk << 5) + ((lane >> 4) << 3) + (i & 7);
    v = f2bf(We2[k * 512 + n]);
  } else if (idx < 589824) {
    int i = idx - 327680, lane = (i >> 3) & 63, t2 = i >> 9;
    int kk = t2 & 15, nf = t2 >> 4;
    int n = (nf << 4) + (lane & 15), k = (kk << 5) + ((lane >> 4) << 3) + (i & 7);
    v = f2bf(We3[k * 512 + n]);
  } else if (idx < 851968) {
    int i = idx - 589824, lane = (i >> 3) & 63, t2 = i >> 9;
    int kk = t2 & 15, nf = t2 >> 4;
    int n = (nf << 4) + (lane & 15), k = (kk << 5) + ((lane >> 4) << 3) + (i & 7);
    v = f2bf(Wd1[k * 512 + n]);
  } else if (idx < 917504) {
    int i = idx - 851968, lane = (i >> 3) & 63, t2 = i >> 9;
    int kk = t2 & 15, nf = t2 >> 4;
    int n = (nf << 4) + (lane & 15), k = (kk << 5) + ((lane >> 4) << 3) + (i & 7);
    v = f2bf(Wd2[k * 128 + n]);
  } else {
    int i = idx - 917504, lane = (i >> 3) & 63, t2 = i >> 9;
    int kk = t2 & 15, nf = t2 >> 4;
    int n = (nf << 4) + (lane & 15), k = (kk << 5) + ((lane >> 4) << 3) + (i & 7);
    v = f2bf(W[(n << 9) + k]);
  }
  wt[idx] = v;
}

__global__ void sentinel_k(float* out, float v) { out[0] = v; }

extern "C" void kernel_launch(void* const* d_in, const int* in_sizes, int n_in,
                              void* d_out, int out_size, void* d_ws, size_t ws_size,
                              hipStream_t stream) {
  const float* in_seq = (const float*)d_in[0];
  const float* We1 = (const float*)d_in[1];
  const float* be1 = (const float*)d_in[2];
  const float* We2 = (const float*)d_in[3];
  const float* be2 = (const float*)d_in[4];
  const float* We3 = (const float*)d_in[5];
  const float* be3 = (const float*)d_in[6];
  const float* Wd1 = (const float*)d_in[7];
  const float* bd1 = (const float*)d_in[8];
  const float* Wd2 = (const float*)d_in[9];
  const float* bd2 = (const float*)d_in[10];
  const float* W   = (const float*)d_in[11];

  const int NROW = B_SZ * T_SZ;                       // 65536
  const size_t OFF_XSEQ = 0;                          // 67,108,864 B
  const size_t OFF_WT   = (size_t)NROW * HID * 2;     // 67,108,864
  const size_t REQUIRED = OFF_WT + 2359296;           // 69,468,160

  float* outp = (float*)d_out;
  float* outr = outp + (size_t)NROW * IN_D;

  if (ws_size < REQUIRED) {
    sentinel_k<<<1, 1, 0, stream>>>(outp, (float)(ws_size >> 20));
    return;
  }

  char* ws = (char*)d_ws;
  unsigned short* xseq = (unsigned short*)(ws + OFF_XSEQ);  // reused as xsall
  unsigned short* wt   = (unsigned short*)(ws + OFF_WT);
  unsigned short* Wd1t = wt + 589824;
  unsigned short* Wd2t = wt + 851968;
  unsigned short* Wrec = wt + 917504;

  prep_k<<<4608, 256, 0, stream>>>(We1, We2, We3, Wd1, Wd2, W, wt);
  enc5_k<<<512, 1024, 0, stream>>>(in_seq, wt, be1, be2, be3,
                                   Wd1t, Wd2t, bd1, bd2, xseq, outr);
  rec_all_k<<<NCHAIN, 512, 0, stream>>>(Wrec, xseq);
  dec_fused_k<<<512, 1024, 0, stream>>>(xseq, Wd1t, Wd2t, bd1, bd2, outp);
}